// Round 1
// baseline (844.694 us; speedup 1.0000x reference)
//
#include <hip/hip_runtime.h>

// MultiLabelAttention: out[b,l,h] = softmax_s(mask(W[l,:]·X[b,s,:])) · X[b,s,h]
// B=64 S=512 H=1024 L=512, fp32 in/out.
//
// R2: two-phase scheme.
//  prep_x / prep_w: one bandwidth-bound pass splits fp32 -> bf16 hi/lo planes
//    (Xhi, Xlo, Whi, Wlo) and materializes XhiT = per-batch V^T (bf16 hi).
//  mla_fused2: flash-style fused kernel, M=32 l-rows/block, S in 128-col steps.
//    GEMM1 loads bf16 frags directly (no split8 VALU). GEMM2 reads V B-frags
//    straight from XhiT in global (L2-hot, 1 MB/batch) -- fragV LDS staging
//    deleted entirely. P exchange via LDS only (8 ds_read_b128 per step).
//  Numerics identical to R1 kernel (same split, same 3-MFMA order, PV in bf16).
//  Fallback: if ws_size < 194 MB, launch the R1 kernel unchanged.

typedef float  f4_t  __attribute__((ext_vector_type(4)));
typedef __bf16 bf8_t __attribute__((ext_vector_type(8)));
typedef __bf16 bf4_t __attribute__((ext_vector_type(4)));

constexpr int Sn = 512, Hn = 1024, Ln = 512, Bn = 64;
#define NEGINF (-1e9f)

__device__ __forceinline__ void split8(f4_t a, f4_t b, bf8_t& hi, bf8_t& lo) {
#pragma unroll
  for (int i = 0; i < 4; ++i) {
    float x = a[i];
    __bf16 h = (__bf16)x;
    hi[i] = h;
    lo[i] = (__bf16)(x - (float)h);
  }
#pragma unroll
  for (int i = 0; i < 4; ++i) {
    float x = b[i];
    __bf16 h = (__bf16)x;
    hi[4 + i] = h;
    lo[4 + i] = (__bf16)(x - (float)h);
  }
}

__device__ __forceinline__ void split4(f4_t x, bf4_t& hi, bf4_t& lo) {
#pragma unroll
  for (int i = 0; i < 4; ++i) {
    float v = x[i];
    __bf16 h = (__bf16)v;
    hi[i] = h;
    lo[i] = (__bf16)(v - (float)h);
  }
}

// ---------------------------------------------------------------------------
// prep_w: W[512,1024] fp32 -> Whi, Wlo bf16 planes. 512 blocks x 256 thr.
// ---------------------------------------------------------------------------
__global__ void prep_w(const float* __restrict__ W, __bf16* __restrict__ Whi,
                       __bf16* __restrict__ Wlo) {
  const int i = (blockIdx.x * 256 + threadIdx.x) * 4;
  f4_t x = *(const f4_t*)(W + i);
  bf4_t hi, lo;
  split4(x, hi, lo);
  *(bf4_t*)(Whi + i) = hi;
  *(bf4_t*)(Wlo + i) = lo;
}

// ---------------------------------------------------------------------------
// prep_x: X[64,512,1024] fp32 -> Xhi, Xlo [b][s][h] bf16 and XhT [b][h][s]
// bf16 (hi only; this is exactly the bf16 V used by GEMM2).
// 64x64 tile transpose through LDS. 8192 blocks x 256 thr.
// ---------------------------------------------------------------------------
__global__ void prep_x(const float* __restrict__ X, __bf16* __restrict__ Xhi,
                       __bf16* __restrict__ Xlo, __bf16* __restrict__ XhT) {
  __shared__ __bf16 T[64][72];  // [h][s] tile, pad 64->72 (16B-aligned rows)
  const int bid = blockIdx.x;
  const int b   = bid >> 7;          // 128 tiles per batch
  const int t   = bid & 127;
  const int s0  = (t >> 4) << 6;     // 8 s-tiles
  const int h0  = (t & 15) << 6;     // 16 h-tiles
  const int tid = threadIdx.x;
  const int hq  = tid & 15;          // h group: 4 floats each
  const int sr  = tid >> 4;          // s row 0..15 (x4 iters)

  const float* xb = X + ((size_t)(b * Sn + s0 + sr)) * Hn + h0 + hq * 4;
  __bf16* xhib = Xhi + ((size_t)(b * Sn + s0 + sr)) * Hn + h0 + hq * 4;
  __bf16* xlob = Xlo + ((size_t)(b * Sn + s0 + sr)) * Hn + h0 + hq * 4;
#pragma unroll
  for (int r = 0; r < 4; ++r) {
    f4_t x = *(const f4_t*)(xb + (size_t)(r * 16) * Hn);
    bf4_t hi, lo;
    split4(x, hi, lo);
    *(bf4_t*)(xhib + (size_t)(r * 16) * Hn) = hi;
    *(bf4_t*)(xlob + (size_t)(r * 16) * Hn) = lo;
#pragma unroll
    for (int i = 0; i < 4; ++i) T[hq * 4 + i][sr + r * 16] = hi[i];
  }
  __syncthreads();
  // write XhT rows (h fixed, s contiguous): 64 rows x 128 B
  const int hr = tid >> 2;
  const int sc = (tid & 3) * 16;
  bf8_t v0 = *(const bf8_t*)&T[hr][sc];
  bf8_t v1 = *(const bf8_t*)&T[hr][sc + 8];
  __bf16* dst = XhT + ((size_t)(b * Hn + h0 + hr)) * Sn + s0 + sc;
  *(bf8_t*)dst = v0;
  *(bf8_t*)(dst + 8) = v1;
}

// ---------------------------------------------------------------------------
// mla_fused2: the fused kernel on pre-split bf16 planes.
// ---------------------------------------------------------------------------
__global__ __launch_bounds__(256, 2)
void mla_fused2(const __bf16* __restrict__ Xhi, const __bf16* __restrict__ Xlo,
                const __bf16* __restrict__ XhT, const int* __restrict__ AM,
                const __bf16* __restrict__ Whi, const __bf16* __restrict__ Wlo,
                float* __restrict__ Out) {
  const int bl   = blockIdx.x;
  const int b    = bl >> 4;          // 16 l-tiles per batch
  const int l0   = (bl & 15) * 32;
  const int tid  = threadIdx.x;
  const int w    = tid >> 6;         // wave 0..3
  const int lane = tid & 63;
  const int n16  = lane & 15;
  const int quad = lane >> 4;

  __shared__ __bf16 fragP[32][136];  // 8.5 KB P exchange (A-frag layout)
  __shared__ float  red[2][4][32];   // 1 KB per-wave row max / row sum

  const f4_t fzero = {0.f, 0.f, 0.f, 0.f};
  const f4_t fneg  = {NEGINF, NEGINF, NEGINF, NEGINF};

  // O accumulator: wave owns h-range [w*256, w*256+256)
  f4_t oacc[2][16];
#pragma unroll
  for (int mt = 0; mt < 2; ++mt)
#pragma unroll
    for (int nt = 0; nt < 16; ++nt) oacc[mt][nt] = fzero;

  float m_pr[2][4], l_pr[2][4];
#pragma unroll
  for (int mt = 0; mt < 2; ++mt)
#pragma unroll
    for (int r = 0; r < 4; ++r) { m_pr[mt][r] = -3e38f; l_pr[mt][r] = 0.f; }

  // Q frag bases (constant across steps)
  const __bf16* q0 = Whi + (size_t)(l0 + n16) * Hn + quad * 8;
  const __bf16* q1 = q0 + 16 * Hn;
  const __bf16* p0 = Wlo + (size_t)(l0 + n16) * Hn + quad * 8;
  const __bf16* p1 = p0 + 16 * Hn;
  // V^T base for this wave's h-range
  const __bf16* vb = XhT + ((size_t)b * Hn + w * 256 + n16) * Sn + quad * 8;

  for (int step = 0; step < 4; ++step) {
    const int s0 = step * 128;

    // -------- GEMM1: scores[32,128], bf16 frags straight from global --------
    f4_t sacc[2][2];
    sacc[0][0] = fzero; sacc[0][1] = fzero; sacc[1][0] = fzero; sacc[1][1] = fzero;

    const __bf16* k0 = Xhi + ((size_t)b * Sn + s0 + w * 32 + n16) * Hn + quad * 8;
    const __bf16* k1 = k0 + 16 * Hn;
    const __bf16* c0 = Xlo + ((size_t)b * Sn + s0 + w * 32 + n16) * Hn + quad * 8;
    const __bf16* c1 = c0 + 16 * Hn;

#pragma unroll 2
    for (int hk = 0; hk < Hn; hk += 32) {
      bf8_t qh0 = *(const bf8_t*)(q0 + hk);
      bf8_t qh1 = *(const bf8_t*)(q1 + hk);
      bf8_t ql0 = *(const bf8_t*)(p0 + hk);
      bf8_t ql1 = *(const bf8_t*)(p1 + hk);
      bf8_t kh0 = *(const bf8_t*)(k0 + hk);
      bf8_t kh1 = *(const bf8_t*)(k1 + hk);
      bf8_t kl0 = *(const bf8_t*)(c0 + hk);
      bf8_t kl1 = *(const bf8_t*)(c1 + hk);
      // mt=0
      {
        f4_t c = sacc[0][0];
        c = __builtin_amdgcn_mfma_f32_16x16x32_bf16(qh0, kh0, c, 0, 0, 0);
        c = __builtin_amdgcn_mfma_f32_16x16x32_bf16(qh0, kl0, c, 0, 0, 0);
        c = __builtin_amdgcn_mfma_f32_16x16x32_bf16(ql0, kh0, c, 0, 0, 0);
        sacc[0][0] = c;
        c = sacc[0][1];
        c = __builtin_amdgcn_mfma_f32_16x16x32_bf16(qh0, kh1, c, 0, 0, 0);
        c = __builtin_amdgcn_mfma_f32_16x16x32_bf16(qh0, kl1, c, 0, 0, 0);
        c = __builtin_amdgcn_mfma_f32_16x16x32_bf16(ql0, kh1, c, 0, 0, 0);
        sacc[0][1] = c;
      }
      // mt=1
      {
        f4_t c = sacc[1][0];
        c = __builtin_amdgcn_mfma_f32_16x16x32_bf16(qh1, kh0, c, 0, 0, 0);
        c = __builtin_amdgcn_mfma_f32_16x16x32_bf16(qh1, kl0, c, 0, 0, 0);
        c = __builtin_amdgcn_mfma_f32_16x16x32_bf16(ql1, kh0, c, 0, 0, 0);
        sacc[1][0] = c;
        c = sacc[1][1];
        c = __builtin_amdgcn_mfma_f32_16x16x32_bf16(qh1, kh1, c, 0, 0, 0);
        c = __builtin_amdgcn_mfma_f32_16x16x32_bf16(qh1, kl1, c, 0, 0, 0);
        c = __builtin_amdgcn_mfma_f32_16x16x32_bf16(ql1, kh1, c, 0, 0, 0);
        sacc[1][1] = c;
      }
    }

    // -------- mask --------
    {
      const int* mrow = AM + b * Sn + s0 + w * 32 + n16;
      int mk0 = mrow[0];
      int mk1 = mrow[16];
      if (!mk0) { sacc[0][0] = fneg; sacc[1][0] = fneg; }
      if (!mk1) { sacc[0][1] = fneg; sacc[1][1] = fneg; }
    }

    // -------- online softmax (2 barriers) --------
    float rmx[2][4];
#pragma unroll
    for (int mt = 0; mt < 2; ++mt)
#pragma unroll
      for (int r = 0; r < 4; ++r) {
        float v = fmaxf(sacc[mt][0][r], sacc[mt][1][r]);
        v = fmaxf(v, __shfl_xor(v, 1));
        v = fmaxf(v, __shfl_xor(v, 2));
        v = fmaxf(v, __shfl_xor(v, 4));
        v = fmaxf(v, __shfl_xor(v, 8));
        rmx[mt][r] = v;
      }
    if (n16 == 0) {
#pragma unroll
      for (int mt = 0; mt < 2; ++mt)
#pragma unroll
        for (int r = 0; r < 4; ++r)
          red[0][w][mt * 16 + quad * 4 + r] = rmx[mt][r];
    }
    __syncthreads();  // barrier A

    float al[2][4], psum[2][4];
#pragma unroll
    for (int mt = 0; mt < 2; ++mt)
#pragma unroll
      for (int r = 0; r < 4; ++r) {
        const int row = mt * 16 + quad * 4 + r;
        float bm = fmaxf(fmaxf(red[0][0][row], red[0][1][row]),
                         fmaxf(red[0][2][row], red[0][3][row]));
        float mn = fmaxf(m_pr[mt][r], bm);
        al[mt][r] = __expf(m_pr[mt][r] - mn);
        m_pr[mt][r] = mn;
        psum[mt][r] = 0.f;
      }

#pragma unroll
    for (int mt = 0; mt < 2; ++mt)
#pragma unroll
      for (int nt = 0; nt < 2; ++nt)
#pragma unroll
        for (int r = 0; r < 4; ++r) {
          const int row = mt * 16 + quad * 4 + r;
          float p = __expf(sacc[mt][nt][r] - m_pr[mt][r]);
          psum[mt][r] += p;
          fragP[row][w * 32 + nt * 16 + n16] = (__bf16)p;
        }

#pragma unroll
    for (int mt = 0; mt < 2; ++mt)
#pragma unroll
      for (int r = 0; r < 4; ++r) {
        float v = psum[mt][r];
        v += __shfl_xor(v, 1);
        v += __shfl_xor(v, 2);
        v += __shfl_xor(v, 4);
        v += __shfl_xor(v, 8);
        if (n16 == 0) red[1][w][mt * 16 + quad * 4 + r] = v;
      }
    __syncthreads();  // barrier B

#pragma unroll
    for (int mt = 0; mt < 2; ++mt)
#pragma unroll
      for (int r = 0; r < 4; ++r) {
        const int row = mt * 16 + quad * 4 + r;
        float bs = red[1][0][row] + red[1][1][row] + red[1][2][row] + red[1][3][row];
        l_pr[mt][r] = l_pr[mt][r] * al[mt][r] + bs;
      }
#pragma unroll
    for (int mt = 0; mt < 2; ++mt)
#pragma unroll
      for (int nt = 0; nt < 16; ++nt)
#pragma unroll
        for (int r = 0; r < 4; ++r) oacc[mt][nt][r] *= al[mt][r];

    // -------- GEMM2: O += P[32,128] x V[128,1024], V straight from XhT --------
    // hoist all P A-frags for this step: 8 ds_read_b128 total
    bf8_t pa[2][4];
#pragma unroll
    for (int kk = 0; kk < 4; ++kk) {
      pa[0][kk] = *(const bf8_t*)&fragP[n16][kk * 32 + quad * 8];
      pa[1][kk] = *(const bf8_t*)&fragP[16 + n16][kk * 32 + quad * 8];
    }

#pragma unroll
    for (int hc = 0; hc < 8; ++hc) {
      const __bf16* v0 = vb + (size_t)(hc * 32) * Sn + s0;
      const __bf16* v1 = v0 + 16 * Sn;
#pragma unroll
      for (int kk = 0; kk < 4; ++kk) {
        bf8_t vv0 = *(const bf8_t*)(v0 + kk * 32);
        bf8_t vv1 = *(const bf8_t*)(v1 + kk * 32);
        oacc[0][hc * 2]     = __builtin_amdgcn_mfma_f32_16x16x32_bf16(
            pa[0][kk], vv0, oacc[0][hc * 2], 0, 0, 0);
        oacc[1][hc * 2]     = __builtin_amdgcn_mfma_f32_16x16x32_bf16(
            pa[1][kk], vv0, oacc[1][hc * 2], 0, 0, 0);
        oacc[0][hc * 2 + 1] = __builtin_amdgcn_mfma_f32_16x16x32_bf16(
            pa[0][kk], vv1, oacc[0][hc * 2 + 1], 0, 0, 0);
        oacc[1][hc * 2 + 1] = __builtin_amdgcn_mfma_f32_16x16x32_bf16(
            pa[1][kk], vv1, oacc[1][hc * 2 + 1], 0, 0, 0);
      }
    }
    // fragP overwritten only after next step's barrier A (pa already in regs)
  }

  // -------- epilogue: O /= l, store --------
  float* ob = Out + ((size_t)b * Ln + l0) * Hn;
#pragma unroll
  for (int mt = 0; mt < 2; ++mt)
#pragma unroll
    for (int r = 0; r < 4; ++r) {
      const int row = mt * 16 + quad * 4 + r;
      const float inv = 1.f / l_pr[mt][r];
#pragma unroll
      for (int nt = 0; nt < 16; ++nt) {
        ob[(size_t)row * Hn + w * 256 + nt * 16 + n16] = oacc[mt][nt][r] * inv;
      }
    }
}

// ---------------------------------------------------------------------------
// R1 kernel, kept verbatim as fallback when ws is too small.
// ---------------------------------------------------------------------------
__global__ __launch_bounds__(256, 2)
void mla_fused(const float* __restrict__ X, const int* __restrict__ AM,
               const float* __restrict__ W, float* __restrict__ Out) {
  const int bl   = blockIdx.x;
  const int b    = bl >> 4;
  const int l0   = (bl & 15) * 32;
  const int tid  = threadIdx.x;
  const int w    = tid >> 6;
  const int lane = tid & 63;
  const int n16  = lane & 15;
  const int quad = lane >> 4;

  __shared__ __bf16 fragP[32][136];
  __shared__ __bf16 fragV[4][32][136];
  __shared__ float  red[2][4][32];

  const f4_t fzero = {0.f, 0.f, 0.f, 0.f};
  const f4_t fneg  = {NEGINF, NEGINF, NEGINF, NEGINF};

  f4_t oacc[2][16];
#pragma unroll
  for (int mt = 0; mt < 2; ++mt)
#pragma unroll
    for (int nt = 0; nt < 16; ++nt) oacc[mt][nt] = fzero;

  float m_pr[2][4], l_pr[2][4];
#pragma unroll
  for (int mt = 0; mt < 2; ++mt)
#pragma unroll
    for (int r = 0; r < 4; ++r) { m_pr[mt][r] = -3e38f; l_pr[mt][r] = 0.f; }

  const float* Xb = X + (size_t)b * Sn * Hn;

  for (int step = 0; step < 4; ++step) {
    const int s0 = step * 128;

    f4_t sacc[2][2];
    sacc[0][0] = fzero; sacc[0][1] = fzero; sacc[1][0] = fzero; sacc[1][1] = fzero;

    const float* q0 = W  + (size_t)(l0 + n16) * Hn + quad * 8;
    const float* q1 = q0 + 16 * Hn;
    const float* k0 = Xb + (size_t)(s0 + w * 32 + n16) * Hn + quad * 8;
    const float* k1 = k0 + 16 * Hn;

    for (int hk = 0; hk < Hn; hk += 32) {
      bf8_t qh[2], ql[2], kh[2], kl[2];
      {
        f4_t a0 = *(const f4_t*)(q0 + hk);
        f4_t a1 = *(const f4_t*)(q0 + hk + 4);
        f4_t a2 = *(const f4_t*)(q1 + hk);
        f4_t a3 = *(const f4_t*)(q1 + hk + 4);
        f4_t c0 = *(const f4_t*)(k0 + hk);
        f4_t c1 = *(const f4_t*)(k0 + hk + 4);
        f4_t c2 = *(const f4_t*)(k1 + hk);
        f4_t c3 = *(const f4_t*)(k1 + hk + 4);
        split8(a0, a1, qh[0], ql[0]);
        split8(a2, a3, qh[1], ql[1]);
        split8(c0, c1, kh[0], kl[0]);
        split8(c2, c3, kh[1], kl[1]);
      }
#pragma unroll
      for (int mt = 0; mt < 2; ++mt)
#pragma unroll
        for (int nt = 0; nt < 2; ++nt) {
          f4_t c = sacc[mt][nt];
          c = __builtin_amdgcn_mfma_f32_16x16x32_bf16(qh[mt], kh[nt], c, 0, 0, 0);
          c = __builtin_amdgcn_mfma_f32_16x16x32_bf16(qh[mt], kl[nt], c, 0, 0, 0);
          c = __builtin_amdgcn_mfma_f32_16x16x32_bf16(ql[mt], kh[nt], c, 0, 0, 0);
          sacc[mt][nt] = c;
        }
    }

    {
      const int* mrow = AM + b * Sn + s0 + w * 32 + n16;
      int mk0 = mrow[0];
      int mk1 = mrow[16];
      if (!mk0) { sacc[0][0] = fneg; sacc[1][0] = fneg; }
      if (!mk1) { sacc[0][1] = fneg; sacc[1][1] = fneg; }
    }

    float rmx[2][4];
#pragma unroll
    for (int mt = 0; mt < 2; ++mt)
#pragma unroll
      for (int r = 0; r < 4; ++r) {
        float v = fmaxf(sacc[mt][0][r], sacc[mt][1][r]);
        v = fmaxf(v, __shfl_xor(v, 1));
        v = fmaxf(v, __shfl_xor(v, 2));
        v = fmaxf(v, __shfl_xor(v, 4));
        v = fmaxf(v, __shfl_xor(v, 8));
        rmx[mt][r] = v;
      }
    if (n16 == 0) {
#pragma unroll
      for (int mt = 0; mt < 2; ++mt)
#pragma unroll
        for (int r = 0; r < 4; ++r)
          red[0][w][mt * 16 + quad * 4 + r] = rmx[mt][r];
    }
    __syncthreads();

    float al[2][4], psum[2][4];
#pragma unroll
    for (int mt = 0; mt < 2; ++mt)
#pragma unroll
      for (int r = 0; r < 4; ++r) {
        const int row = mt * 16 + quad * 4 + r;
        float bm = fmaxf(fmaxf(red[0][0][row], red[0][1][row]),
                         fmaxf(red[0][2][row], red[0][3][row]));
        float mn = fmaxf(m_pr[mt][r], bm);
        al[mt][r] = __expf(m_pr[mt][r] - mn);
        m_pr[mt][r] = mn;
        psum[mt][r] = 0.f;
      }

#pragma unroll
    for (int mt = 0; mt < 2; ++mt)
#pragma unroll
      for (int nt = 0; nt < 2; ++nt)
#pragma unroll
        for (int r = 0; r < 4; ++r) {
          const int row = mt * 16 + quad * 4 + r;
          float p = __expf(sacc[mt][nt][r] - m_pr[mt][r]);
          psum[mt][r] += p;
          fragP[row][w * 32 + nt * 16 + n16] = (__bf16)p;
        }

#pragma unroll
    for (int mt = 0; mt < 2; ++mt)
#pragma unroll
      for (int r = 0; r < 4; ++r) {
        float v = psum[mt][r];
        v += __shfl_xor(v, 1);
        v += __shfl_xor(v, 2);
        v += __shfl_xor(v, 4);
        v += __shfl_xor(v, 8);
        if (n16 == 0) red[1][w][mt * 16 + quad * 4 + r] = v;
      }
    __syncthreads();

#pragma unroll
    for (int mt = 0; mt < 2; ++mt)
#pragma unroll
      for (int r = 0; r < 4; ++r) {
        const int row = mt * 16 + quad * 4 + r;
        float bs = red[1][0][row] + red[1][1][row] + red[1][2][row] + red[1][3][row];
        l_pr[mt][r] = l_pr[mt][r] * al[mt][r] + bs;
      }
#pragma unroll
    for (int mt = 0; mt < 2; ++mt)
#pragma unroll
      for (int nt = 0; nt < 16; ++nt)
#pragma unroll
        for (int r = 0; r < 4; ++r) oacc[mt][nt][r] *= al[mt][r];

    const int colg = lane & 7;
    const int sg   = lane >> 3;
    for (int hc = 0; hc < 8; ++hc) {
      const int h0 = w * 256 + hc * 32;
      const float* vsrc = Xb + (size_t)(s0 + sg * 4) * Hn + h0 + colg * 4;
#pragma unroll
      for (int it = 0; it < 4; ++it) {
        const float* p = vsrc + (size_t)(it * 32) * Hn;
        f4_t r0v = *(const f4_t*)(p);
        f4_t r1v = *(const f4_t*)(p + Hn);
        f4_t r2v = *(const f4_t*)(p + 2 * Hn);
        f4_t r3v = *(const f4_t*)(p + 3 * Hn);
        const int si = it * 32 + sg * 4;
#pragma unroll
        for (int c = 0; c < 4; ++c) {
          bf4_t v;
          v[0] = (__bf16)r0v[c];
          v[1] = (__bf16)r1v[c];
          v[2] = (__bf16)r2v[c];
          v[3] = (__bf16)r3v[c];
          *(bf4_t*)&fragV[w][colg * 4 + c][si] = v;
        }
      }
#pragma unroll
      for (int kk = 0; kk < 4; ++kk) {
        bf8_t pa0 = *(const bf8_t*)&fragP[n16][kk * 32 + quad * 8];
        bf8_t pa1 = *(const bf8_t*)&fragP[16 + n16][kk * 32 + quad * 8];
#pragma unroll
        for (int ntl = 0; ntl < 2; ++ntl) {
          bf8_t vv = *(const bf8_t*)&fragV[w][ntl * 16 + n16][kk * 32 + quad * 8];
          oacc[0][hc * 2 + ntl] =
              __builtin_amdgcn_mfma_f32_16x16x32_bf16(pa0, vv, oacc[0][hc * 2 + ntl], 0, 0, 0);
          oacc[1][hc * 2 + ntl] =
              __builtin_amdgcn_mfma_f32_16x16x32_bf16(pa1, vv, oacc[1][hc * 2 + ntl], 0, 0, 0);
        }
      }
    }
  }

  float* ob = Out + ((size_t)b * Ln + l0) * Hn;
#pragma unroll
  for (int mt = 0; mt < 2; ++mt)
#pragma unroll
    for (int r = 0; r < 4; ++r) {
      const int row = mt * 16 + quad * 4 + r;
      const float inv = 1.f / l_pr[mt][r];
#pragma unroll
      for (int nt = 0; nt < 16; ++nt) {
        ob[(size_t)row * Hn + w * 256 + nt * 16 + n16] = oacc[mt][nt][r] * inv;
      }
    }
}

extern "C" void kernel_launch(void* const* d_in, const int* in_sizes, int n_in,
                              void* d_out, int out_size, void* d_ws, size_t ws_size,
                              hipStream_t stream) {
  (void)in_sizes; (void)n_in; (void)out_size;
  const float* X  = (const float*)d_in[0];   // sequence_output [64,512,1024]
  const int*   AM = (const int*)d_in[1];     // attention_mask  [64,512]
  const float* W  = (const float*)d_in[2];   // attention_weights [512,1024]
  float* Out = (float*)d_out;                // [64,512,1024]

  // ws layout (bytes): Xhi 64MiB | Xlo 64MiB | XhT 64MiB | Whi 1MiB | Wlo 1MiB
  const size_t SZ_X = (size_t)Bn * Sn * Hn * sizeof(__bf16);  // 67108864
  const size_t SZ_W = (size_t)Ln * Hn * sizeof(__bf16);       // 1048576
  const size_t NEED = 3 * SZ_X + 2 * SZ_W;                    // 203423744

  if (d_ws != nullptr && ws_size >= NEED) {
    char* wsb = (char*)d_ws;
    __bf16* Xhi = (__bf16*)(wsb);
    __bf16* Xlo = (__bf16*)(wsb + SZ_X);
    __bf16* XhT = (__bf16*)(wsb + 2 * SZ_X);
    __bf16* Whi = (__bf16*)(wsb + 3 * SZ_X);
    __bf16* Wlo = (__bf16*)(wsb + 3 * SZ_X + SZ_W);
    prep_x<<<dim3(64 * 128), dim3(256), 0, stream>>>(X, Xhi, Xlo, XhT);
    prep_w<<<dim3(512), dim3(256), 0, stream>>>(W, Whi, Wlo);
    mla_fused2<<<dim3(64 * 16), dim3(256), 0, stream>>>(Xhi, Xlo, XhT, AM, Whi, Wlo, Out);
  } else {
    mla_fused<<<dim3(64 * 16), dim3(256), 0, stream>>>(X, AM, W, Out);
  }
}

// Round 2
// 656.992 us; speedup vs baseline: 1.2857x; 1.2857x over previous
//
#include <hip/hip_runtime.h>

// MultiLabelAttention: out[b,l,h] = softmax_s(mask(W[l,:]·X[b,s,:])) · X[b,s,h]
// B=64 S=512 H=1024 L=512, fp32 in/out.
//
// R3: async-staged flash kernel on chunked pre-swizzled bf16 layouts.
//  prep_x: X fp32 -> Xhi_c/Xlo_c [b][hk/32][512 s][32 h] (bank-swizzle baked in)
//          and Vc [b][h/32][s/128][32 h][128 s] (V^T tiles, natural layout).
//  prep_w: W fp32 -> Whi_c/Wlo_c [hk/32][512 l][32 h] (swizzled).
//  mla_fused3: GEMM1 consumes Q/K via global_load_lds double-buffered LDS
//          (2-phase, one barrier per 32-h chunk); GEMM2 reads dense Vc tiles
//          straight from global (L2-hot via XCD-aware block swizzle).
//  Numerics identical to R2 (same split, same MFMA order, PV bf16-hi).
//  Fallback: if ws too small, R1 kernel (raw inputs) unchanged.

typedef float  f4_t  __attribute__((ext_vector_type(4)));
typedef __bf16 bf8_t __attribute__((ext_vector_type(8)));
typedef __bf16 bf4_t __attribute__((ext_vector_type(4)));

constexpr int Sn = 512, Hn = 1024, Ln = 512, Bn = 64;
#define NEGINF (-1e9f)

// async global->LDS, 16 B per lane; LDS dest is wave-uniform base + lane*16
#define GL16(gsrc, ldst)                                                      \
  __builtin_amdgcn_global_load_lds(                                           \
      (const __attribute__((address_space(1))) void*)(gsrc),                  \
      (__attribute__((address_space(3))) void*)(ldst), 16, 0, 0)

__device__ __forceinline__ void split8(f4_t a, f4_t b, bf8_t& hi, bf8_t& lo) {
#pragma unroll
  for (int i = 0; i < 4; ++i) {
    float x = a[i];
    __bf16 h = (__bf16)x;
    hi[i] = h;
    lo[i] = (__bf16)(x - (float)h);
  }
#pragma unroll
  for (int i = 0; i < 4; ++i) {
    float x = b[i];
    __bf16 h = (__bf16)x;
    hi[4 + i] = h;
    lo[4 + i] = (__bf16)(x - (float)h);
  }
}

// ---------------------------------------------------------------------------
// prep_w: W[512,1024] -> Whi_c/Wlo_c [c][512 l][4 slot][8] with slot-XOR
// swizzle baked in: stored slot holds natural cols (slot^((l>>1)&3))*8.
// 256 blocks x 256 thr, one 16-B unit per thread.
// ---------------------------------------------------------------------------
__global__ void prep_w(const float* __restrict__ W, __bf16* __restrict__ WhiC,
                       __bf16* __restrict__ WloC) {
  const int u = blockIdx.x * 256 + threadIdx.x;  // 65536 units
  const int c = u >> 11;
  const int l = (u >> 2) & 511;
  const int slot = u & 3;
  const int nat = (slot ^ ((l >> 1) & 3)) * 8;
  const float* src = W + (size_t)l * Hn + c * 32 + nat;
  f4_t a = *(const f4_t*)src;
  f4_t b2 = *(const f4_t*)(src + 4);
  bf8_t hi, lo;
  split8(a, b2, hi, lo);
  *(bf8_t*)(WhiC + (size_t)u * 8) = hi;
  *(bf8_t*)(WloC + (size_t)u * 8) = lo;
}

// ---------------------------------------------------------------------------
// prep_x: per block, one [128 s][32 h] tile of X (b, chunk c, s-step st).
//  - write Xhi_c / Xlo_c (chunked, swizzled slots) with 16-B stores
//  - LDS transpose -> Vc tile [32 h][128 s] (natural, bf16-hi)
// grid 8192 = 64 b x 32 c x 4 st, 256 thr.
// ---------------------------------------------------------------------------
__global__ __launch_bounds__(256)
void prep_x(const float* __restrict__ X, __bf16* __restrict__ XhiC,
            __bf16* __restrict__ XloC, __bf16* __restrict__ Vc) {
  __shared__ __bf16 T[128][38];  // 76-B rows: 4B-aligned uint stores, spread banks
  const int bid = blockIdx.x;
  const int b  = bid >> 7;
  const int c  = (bid >> 2) & 31;
  const int st = bid & 3;
  const int s0 = st * 128;
  const int t  = threadIdx.x;

#pragma unroll
  for (int i = 0; i < 2; ++i) {
    const int u = i * 256 + t;        // 512 units of 16 B (out)
    const int row = u >> 2;           // s within tile
    const int slot = u & 3;
    const int nat = (slot ^ ((row >> 1) & 3)) * 8;  // natural col group
    const float* src = X + ((size_t)(b * Sn + s0 + row)) * Hn + c * 32 + nat;
    f4_t a = *(const f4_t*)src;
    f4_t b2 = *(const f4_t*)(src + 4);
    bf8_t hi, lo;
    split8(a, b2, hi, lo);
    const size_t o = (((size_t)(b * 32 + c) * 512) + s0 + row) * 32 + slot * 8;
    *(bf8_t*)(XhiC + o) = hi;
    *(bf8_t*)(XloC + o) = lo;
    // stage hi at NATURAL cols for the transpose
    union { bf8_t v; unsigned int uu[4]; } cv;
    cv.v = hi;
    unsigned int* dT = (unsigned int*)&T[row][nat];
#pragma unroll
    for (int k = 0; k < 4; ++k) dT[k] = cv.uu[k];
  }
  __syncthreads();
#pragma unroll
  for (int i = 0; i < 2; ++i) {
    const int u = i * 256 + t;        // 512 units of 16 B (out)
    const int hr = u >> 4;            // h within chunk
    const int sg = (u & 15) * 8;      // s group of 8
    bf8_t o;
#pragma unroll
    for (int k = 0; k < 8; ++k) o[k] = T[sg + k][hr];
    *(bf8_t*)(Vc + ((((size_t)b * 32 + c) * 4 + st) * 32 + hr) * 128 + sg) = o;
  }
}

// ---------------------------------------------------------------------------
// mla_fused3
// ---------------------------------------------------------------------------
__global__ __launch_bounds__(256, 2)
void mla_fused3(const __bf16* __restrict__ XhiC, const __bf16* __restrict__ XloC,
                const __bf16* __restrict__ Vc, const int* __restrict__ AM,
                const __bf16* __restrict__ WhiC, const __bf16* __restrict__ WloC,
                float* __restrict__ Out) {
  // XCD-aware swizzle: batch b -> XCD b&7; 16 l-tiles of a batch temporally
  // adjacent on one XCD so X/V planes (~6 MB/batch) stay L2-hot.
  const int i0 = blockIdx.x;
  const int xcd = i0 & 7, jj = i0 >> 3;
  const int b  = (jj >> 4) * 8 + xcd;
  const int l0 = (jj & 15) * 32;

  const int tid  = threadIdx.x;
  const int w    = tid >> 6;
  const int lane = tid & 63;
  const int n16  = lane & 15;
  const int quad = lane >> 4;
  // bank swizzle: stored slot q holds natural cols (q ^ ((row>>1)&3)); frag
  // rows are n16 + 16k so f(row) = (n16>>1)&3 for all of them.
  const int qoff = (quad ^ ((n16 >> 1) & 3)) * 8;  // element offset in row

  __shared__ __bf16 Kb[2][2][128][32];  // 32 KB: [buf][hi/lo][s][h-chunk]
  __shared__ __bf16 Qb[2][2][32][32];   // 8 KB : [buf][hi/lo][l][h-chunk]
  __shared__ __bf16 fragP[32][136];     // 8.5 KB
  __shared__ float  red[2][4][32];      // 1 KB

  const f4_t fzero = {0.f, 0.f, 0.f, 0.f};
  const f4_t fneg  = {NEGINF, NEGINF, NEGINF, NEGINF};

  f4_t oacc[2][16];
#pragma unroll
  for (int mt = 0; mt < 2; ++mt)
#pragma unroll
    for (int nt = 0; nt < 16; ++nt) oacc[mt][nt] = fzero;

  float m_pr[2][4], l_pr[2][4];
#pragma unroll
  for (int mt = 0; mt < 2; ++mt)
#pragma unroll
    for (int r = 0; r < 4; ++r) { m_pr[mt][r] = -3e38f; l_pr[mt][r] = 0.f; }

  const __bf16* XhiB = XhiC + (size_t)b * (32 * 512 * 32);
  const __bf16* XloB = XloC + (size_t)b * (32 * 512 * 32);
  const __bf16* VcB  = Vc   + (size_t)b * (32 * 4 * 32 * 128);

  // staging roles (per wave): K rows [w*32, w*32+32) both planes (4 issues),
  // plus one quarter of Q (1 issue).
  const int r0 = w * 32;
  const int qhalf = (w & 1) * 16;
  const __bf16* Wsrc = (w < 2) ? WhiC : WloC;

#define STAGE_CHUNK(cc, bb, ss)                                               \
  {                                                                           \
    const __bf16* gk = XhiB + ((size_t)(cc) * 512 + (ss) + r0) * 32 + lane * 8;\
    const __bf16* gl = XloB + ((size_t)(cc) * 512 + (ss) + r0) * 32 + lane * 8;\
    GL16(gk,       &Kb[bb][0][r0][0]);                                        \
    GL16(gk + 512, &Kb[bb][0][r0 + 16][0]);                                   \
    GL16(gl,       &Kb[bb][1][r0][0]);                                        \
    GL16(gl + 512, &Kb[bb][1][r0 + 16][0]);                                   \
    const __bf16* gq = Wsrc + ((size_t)(cc) * 512 + l0 + qhalf) * 32 + lane * 8;\
    GL16(gq, &Qb[bb][w >> 1][qhalf][0]);                                      \
  }

  STAGE_CHUNK(0, 0, 0);  // prologue: step 0 chunk 0

  for (int step = 0; step < 4; ++step) {
    const int s0 = step * 128;
    __syncthreads();  // chunk 0 of this step staged & drained

    // -------- GEMM1: 32 chunks of K=32, double-buffered async staging -----
    f4_t sacc[2][2];
    sacc[0][0] = fzero; sacc[0][1] = fzero; sacc[1][0] = fzero; sacc[1][1] = fzero;

    for (int c = 0; c < 32; ++c) {
      const int bb = c & 1;
      if (c < 31) {
        STAGE_CHUNK(c + 1, bb ^ 1, s0);
      } else if (step < 3) {
        STAGE_CHUNK(0, bb ^ 1, s0 + 128);  // next step's chunk 0 -> buf 0
      }
      bf8_t qh0 = *(const bf8_t*)&Qb[bb][0][n16][qoff];
      bf8_t qh1 = *(const bf8_t*)&Qb[bb][0][n16 + 16][qoff];
      bf8_t ql0 = *(const bf8_t*)&Qb[bb][1][n16][qoff];
      bf8_t ql1 = *(const bf8_t*)&Qb[bb][1][n16 + 16][qoff];
      bf8_t kh0 = *(const bf8_t*)&Kb[bb][0][r0 + n16][qoff];
      bf8_t kh1 = *(const bf8_t*)&Kb[bb][0][r0 + n16 + 16][qoff];
      bf8_t kl0 = *(const bf8_t*)&Kb[bb][1][r0 + n16][qoff];
      bf8_t kl1 = *(const bf8_t*)&Kb[bb][1][r0 + n16 + 16][qoff];
      {
        f4_t cc0 = sacc[0][0];
        cc0 = __builtin_amdgcn_mfma_f32_16x16x32_bf16(qh0, kh0, cc0, 0, 0, 0);
        cc0 = __builtin_amdgcn_mfma_f32_16x16x32_bf16(qh0, kl0, cc0, 0, 0, 0);
        cc0 = __builtin_amdgcn_mfma_f32_16x16x32_bf16(ql0, kh0, cc0, 0, 0, 0);
        sacc[0][0] = cc0;
        f4_t cc1 = sacc[0][1];
        cc1 = __builtin_amdgcn_mfma_f32_16x16x32_bf16(qh0, kh1, cc1, 0, 0, 0);
        cc1 = __builtin_amdgcn_mfma_f32_16x16x32_bf16(qh0, kl1, cc1, 0, 0, 0);
        cc1 = __builtin_amdgcn_mfma_f32_16x16x32_bf16(ql0, kh1, cc1, 0, 0, 0);
        sacc[0][1] = cc1;
        f4_t cc2 = sacc[1][0];
        cc2 = __builtin_amdgcn_mfma_f32_16x16x32_bf16(qh1, kh0, cc2, 0, 0, 0);
        cc2 = __builtin_amdgcn_mfma_f32_16x16x32_bf16(qh1, kl0, cc2, 0, 0, 0);
        cc2 = __builtin_amdgcn_mfma_f32_16x16x32_bf16(ql1, kh0, cc2, 0, 0, 0);
        sacc[1][0] = cc2;
        f4_t cc3 = sacc[1][1];
        cc3 = __builtin_amdgcn_mfma_f32_16x16x32_bf16(qh1, kh1, cc3, 0, 0, 0);
        cc3 = __builtin_amdgcn_mfma_f32_16x16x32_bf16(qh1, kl1, cc3, 0, 0, 0);
        cc3 = __builtin_amdgcn_mfma_f32_16x16x32_bf16(ql1, kh1, cc3, 0, 0, 0);
        sacc[1][1] = cc3;
      }
      __syncthreads();  // drains vmcnt(0): chunk c+1 staged for all waves
    }

    // -------- mask --------
    {
      const int* mrow = AM + b * Sn + s0 + w * 32 + n16;
      int mk0 = mrow[0];
      int mk1 = mrow[16];
      if (!mk0) { sacc[0][0] = fneg; sacc[1][0] = fneg; }
      if (!mk1) { sacc[0][1] = fneg; sacc[1][1] = fneg; }
    }

    // -------- online softmax (2 barriers) --------
    float rmx[2][4];
#pragma unroll
    for (int mt = 0; mt < 2; ++mt)
#pragma unroll
      for (int r = 0; r < 4; ++r) {
        float v = fmaxf(sacc[mt][0][r], sacc[mt][1][r]);
        v = fmaxf(v, __shfl_xor(v, 1));
        v = fmaxf(v, __shfl_xor(v, 2));
        v = fmaxf(v, __shfl_xor(v, 4));
        v = fmaxf(v, __shfl_xor(v, 8));
        rmx[mt][r] = v;
      }
    if (n16 == 0) {
#pragma unroll
      for (int mt = 0; mt < 2; ++mt)
#pragma unroll
        for (int r = 0; r < 4; ++r)
          red[0][w][mt * 16 + quad * 4 + r] = rmx[mt][r];
    }
    __syncthreads();  // barrier A

    float al[2][4], psum[2][4];
#pragma unroll
    for (int mt = 0; mt < 2; ++mt)
#pragma unroll
      for (int r = 0; r < 4; ++r) {
        const int row = mt * 16 + quad * 4 + r;
        float bm = fmaxf(fmaxf(red[0][0][row], red[0][1][row]),
                         fmaxf(red[0][2][row], red[0][3][row]));
        float mn = fmaxf(m_pr[mt][r], bm);
        al[mt][r] = __expf(m_pr[mt][r] - mn);
        m_pr[mt][r] = mn;
        psum[mt][r] = 0.f;
      }

#pragma unroll
    for (int mt = 0; mt < 2; ++mt)
#pragma unroll
      for (int nt = 0; nt < 2; ++nt)
#pragma unroll
        for (int r = 0; r < 4; ++r) {
          const int row = mt * 16 + quad * 4 + r;
          float p = __expf(sacc[mt][nt][r] - m_pr[mt][r]);
          psum[mt][r] += p;
          fragP[row][w * 32 + nt * 16 + n16] = (__bf16)p;
        }

#pragma unroll
    for (int mt = 0; mt < 2; ++mt)
#pragma unroll
      for (int r = 0; r < 4; ++r) {
        float v = psum[mt][r];
        v += __shfl_xor(v, 1);
        v += __shfl_xor(v, 2);
        v += __shfl_xor(v, 4);
        v += __shfl_xor(v, 8);
        if (n16 == 0) red[1][w][mt * 16 + quad * 4 + r] = v;
      }
    __syncthreads();  // barrier B

#pragma unroll
    for (int mt = 0; mt < 2; ++mt)
#pragma unroll
      for (int r = 0; r < 4; ++r) {
        const int row = mt * 16 + quad * 4 + r;
        float bs = red[1][0][row] + red[1][1][row] + red[1][2][row] + red[1][3][row];
        l_pr[mt][r] = l_pr[mt][r] * al[mt][r] + bs;
      }
#pragma unroll
    for (int mt = 0; mt < 2; ++mt)
#pragma unroll
      for (int nt = 0; nt < 16; ++nt)
#pragma unroll
        for (int r = 0; r < 4; ++r) oacc[mt][nt][r] *= al[mt][r];

    // -------- GEMM2: O += P[32,128] x V[128,1024], dense Vc tiles ----------
    bf8_t pa[2][4];
#pragma unroll
    for (int kk = 0; kk < 4; ++kk) {
      pa[0][kk] = *(const bf8_t*)&fragP[n16][kk * 32 + quad * 8];
      pa[1][kk] = *(const bf8_t*)&fragP[16 + n16][kk * 32 + quad * 8];
    }

#pragma unroll
    for (int hc = 0; hc < 8; ++hc) {
      const __bf16* vt = VcB + (((size_t)(w * 8 + hc)) * 4 + step) * 4096;
#pragma unroll
      for (int kk = 0; kk < 4; ++kk) {
        bf8_t vv0 = *(const bf8_t*)(vt + (size_t)n16 * 128 + kk * 32 + quad * 8);
        bf8_t vv1 = *(const bf8_t*)(vt + (size_t)(n16 + 16) * 128 + kk * 32 + quad * 8);
        oacc[0][hc * 2]     = __builtin_amdgcn_mfma_f32_16x16x32_bf16(
            pa[0][kk], vv0, oacc[0][hc * 2], 0, 0, 0);
        oacc[1][hc * 2]     = __builtin_amdgcn_mfma_f32_16x16x32_bf16(
            pa[1][kk], vv0, oacc[1][hc * 2], 0, 0, 0);
        oacc[0][hc * 2 + 1] = __builtin_amdgcn_mfma_f32_16x16x32_bf16(
            pa[0][kk], vv1, oacc[0][hc * 2 + 1], 0, 0, 0);
        oacc[1][hc * 2 + 1] = __builtin_amdgcn_mfma_f32_16x16x32_bf16(
            pa[1][kk], vv1, oacc[1][hc * 2 + 1], 0, 0, 0);
      }
    }
    // fragP overwritten only after next step's barrier A (pa already in regs)
  }

  // -------- epilogue: O /= l, store --------
  float* ob = Out + ((size_t)b * Ln + l0) * Hn;
#pragma unroll
  for (int mt = 0; mt < 2; ++mt)
#pragma unroll
    for (int r = 0; r < 4; ++r) {
      const int row = mt * 16 + quad * 4 + r;
      const float inv = 1.f / l_pr[mt][r];
#pragma unroll
      for (int nt = 0; nt < 16; ++nt) {
        ob[(size_t)row * Hn + w * 256 + nt * 16 + n16] = oacc[mt][nt][r] * inv;
      }
    }
#undef STAGE_CHUNK
}

// ---------------------------------------------------------------------------
// R1 kernel, kept verbatim as fallback when ws is too small (raw inputs).
// ---------------------------------------------------------------------------
__global__ __launch_bounds__(256, 2)
void mla_fused(const float* __restrict__ X, const int* __restrict__ AM,
               const float* __restrict__ W, float* __restrict__ Out) {
  const int bl   = blockIdx.x;
  const int b    = bl >> 4;
  const int l0   = (bl & 15) * 32;
  const int tid  = threadIdx.x;
  const int w    = tid >> 6;
  const int lane = tid & 63;
  const int n16  = lane & 15;
  const int quad = lane >> 4;

  __shared__ __bf16 fragP[32][136];
  __shared__ __bf16 fragV[4][32][136];
  __shared__ float  red[2][4][32];

  const f4_t fzero = {0.f, 0.f, 0.f, 0.f};
  const f4_t fneg  = {NEGINF, NEGINF, NEGINF, NEGINF};

  f4_t oacc[2][16];
#pragma unroll
  for (int mt = 0; mt < 2; ++mt)
#pragma unroll
    for (int nt = 0; nt < 16; ++nt) oacc[mt][nt] = fzero;

  float m_pr[2][4], l_pr[2][4];
#pragma unroll
  for (int mt = 0; mt < 2; ++mt)
#pragma unroll
    for (int r = 0; r < 4; ++r) { m_pr[mt][r] = -3e38f; l_pr[mt][r] = 0.f; }

  const float* Xb = X + (size_t)b * Sn * Hn;

  for (int step = 0; step < 4; ++step) {
    const int s0 = step * 128;

    f4_t sacc[2][2];
    sacc[0][0] = fzero; sacc[0][1] = fzero; sacc[1][0] = fzero; sacc[1][1] = fzero;

    const float* q0 = W  + (size_t)(l0 + n16) * Hn + quad * 8;
    const float* q1 = q0 + 16 * Hn;
    const float* k0 = Xb + (size_t)(s0 + w * 32 + n16) * Hn + quad * 8;
    const float* k1 = k0 + 16 * Hn;

    for (int hk = 0; hk < Hn; hk += 32) {
      bf8_t qh[2], ql[2], kh[2], kl[2];
      {
        f4_t a0 = *(const f4_t*)(q0 + hk);
        f4_t a1 = *(const f4_t*)(q0 + hk + 4);
        f4_t a2 = *(const f4_t*)(q1 + hk);
        f4_t a3 = *(const f4_t*)(q1 + hk + 4);
        f4_t c0 = *(const f4_t*)(k0 + hk);
        f4_t c1 = *(const f4_t*)(k0 + hk + 4);
        f4_t c2 = *(const f4_t*)(k1 + hk);
        f4_t c3 = *(const f4_t*)(k1 + hk + 4);
        split8(a0, a1, qh[0], ql[0]);
        split8(a2, a3, qh[1], ql[1]);
        split8(c0, c1, kh[0], kl[0]);
        split8(c2, c3, kh[1], kl[1]);
      }
#pragma unroll
      for (int mt = 0; mt < 2; ++mt)
#pragma unroll
        for (int nt = 0; nt < 2; ++nt) {
          f4_t c = sacc[mt][nt];
          c = __builtin_amdgcn_mfma_f32_16x16x32_bf16(qh[mt], kh[nt], c, 0, 0, 0);
          c = __builtin_amdgcn_mfma_f32_16x16x32_bf16(qh[mt], kl[nt], c, 0, 0, 0);
          c = __builtin_amdgcn_mfma_f32_16x16x32_bf16(ql[mt], kh[nt], c, 0, 0, 0);
          sacc[mt][nt] = c;
        }
    }

    {
      const int* mrow = AM + b * Sn + s0 + w * 32 + n16;
      int mk0 = mrow[0];
      int mk1 = mrow[16];
      if (!mk0) { sacc[0][0] = fneg; sacc[1][0] = fneg; }
      if (!mk1) { sacc[0][1] = fneg; sacc[1][1] = fneg; }
    }

    float rmx[2][4];
#pragma unroll
    for (int mt = 0; mt < 2; ++mt)
#pragma unroll
      for (int r = 0; r < 4; ++r) {
        float v = fmaxf(sacc[mt][0][r], sacc[mt][1][r]);
        v = fmaxf(v, __shfl_xor(v, 1));
        v = fmaxf(v, __shfl_xor(v, 2));
        v = fmaxf(v, __shfl_xor(v, 4));
        v = fmaxf(v, __shfl_xor(v, 8));
        rmx[mt][r] = v;
      }
    if (n16 == 0) {
#pragma unroll
      for (int mt = 0; mt < 2; ++mt)
#pragma unroll
        for (int r = 0; r < 4; ++r)
          red[0][w][mt * 16 + quad * 4 + r] = rmx[mt][r];
    }
    __syncthreads();

    float al[2][4], psum[2][4];
#pragma unroll
    for (int mt = 0; mt < 2; ++mt)
#pragma unroll
      for (int r = 0; r < 4; ++r) {
        const int row = mt * 16 + quad * 4 + r;
        float bm = fmaxf(fmaxf(red[0][0][row], red[0][1][row]),
                         fmaxf(red[0][2][row], red[0][3][row]));
        float mn = fmaxf(m_pr[mt][r], bm);
        al[mt][r] = __expf(m_pr[mt][r] - mn);
        m_pr[mt][r] = mn;
        psum[mt][r] = 0.f;
      }

#pragma unroll
    for (int mt = 0; mt < 2; ++mt)
#pragma unroll
      for (int nt = 0; nt < 2; ++nt)
#pragma unroll
        for (int r = 0; r < 4; ++r) {
          const int row = mt * 16 + quad * 4 + r;
          float p = __expf(sacc[mt][nt][r] - m_pr[mt][r]);
          psum[mt][r] += p;
          fragP[row][w * 32 + nt * 16 + n16] = (__bf16)p;
        }

#pragma unroll
    for (int mt = 0; mt < 2; ++mt)
#pragma unroll
      for (int r = 0; r < 4; ++r) {
        float v = psum[mt][r];
        v += __shfl_xor(v, 1);
        v += __shfl_xor(v, 2);
        v += __shfl_xor(v, 4);
        v += __shfl_xor(v, 8);
        if (n16 == 0) red[1][w][mt * 16 + quad * 4 + r] = v;
      }
    __syncthreads();

#pragma unroll
    for (int mt = 0; mt < 2; ++mt)
#pragma unroll
      for (int r = 0; r < 4; ++r) {
        const int row = mt * 16 + quad * 4 + r;
        float bs = red[1][0][row] + red[1][1][row] + red[1][2][row] + red[1][3][row];
        l_pr[mt][r] = l_pr[mt][r] * al[mt][r] + bs;
      }
#pragma unroll
    for (int mt = 0; mt < 2; ++mt)
#pragma unroll
      for (int nt = 0; nt < 16; ++nt)
#pragma unroll
        for (int r = 0; r < 4; ++r) oacc[mt][nt][r] *= al[mt][r];

    const int colg = lane & 7;
    const int sg   = lane >> 3;
    for (int hc = 0; hc < 8; ++hc) {
      const int h0 = w * 256 + hc * 32;
      const float* vsrc = Xb + (size_t)(s0 + sg * 4) * Hn + h0 + colg * 4;
#pragma unroll
      for (int it = 0; it < 4; ++it) {
        const float* p = vsrc + (size_t)(it * 32) * Hn;
        f4_t r0v = *(const f4_t*)(p);
        f4_t r1v = *(const f4_t*)(p + Hn);
        f4_t r2v = *(const f4_t*)(p + 2 * Hn);
        f4_t r3v = *(const f4_t*)(p + 3 * Hn);
        const int si = it * 32 + sg * 4;
#pragma unroll
        for (int cix = 0; cix < 4; ++cix) {
          bf4_t v;
          v[0] = (__bf16)r0v[cix];
          v[1] = (__bf16)r1v[cix];
          v[2] = (__bf16)r2v[cix];
          v[3] = (__bf16)r3v[cix];
          *(bf4_t*)&fragV[w][colg * 4 + cix][si] = v;
        }
      }
#pragma unroll
      for (int kk = 0; kk < 4; ++kk) {
        bf8_t pa0 = *(const bf8_t*)&fragP[n16][kk * 32 + quad * 8];
        bf8_t pa1 = *(const bf8_t*)&fragP[16 + n16][kk * 32 + quad * 8];
#pragma unroll
        for (int ntl = 0; ntl < 2; ++ntl) {
          bf8_t vv = *(const bf8_t*)&fragV[w][ntl * 16 + n16][kk * 32 + quad * 8];
          oacc[0][hc * 2 + ntl] =
              __builtin_amdgcn_mfma_f32_16x16x32_bf16(pa0, vv, oacc[0][hc * 2 + ntl], 0, 0, 0);
          oacc[1][hc * 2 + ntl] =
              __builtin_amdgcn_mfma_f32_16x16x32_bf16(pa1, vv, oacc[1][hc * 2 + ntl], 0, 0, 0);
        }
      }
    }
  }

  float* ob = Out + ((size_t)b * Ln + l0) * Hn;
#pragma unroll
  for (int mt = 0; mt < 2; ++mt)
#pragma unroll
    for (int r = 0; r < 4; ++r) {
      const int row = mt * 16 + quad * 4 + r;
      const float inv = 1.f / l_pr[mt][r];
#pragma unroll
      for (int nt = 0; nt < 16; ++nt) {
        ob[(size_t)row * Hn + w * 256 + nt * 16 + n16] = oacc[mt][nt][r] * inv;
      }
    }
}

extern "C" void kernel_launch(void* const* d_in, const int* in_sizes, int n_in,
                              void* d_out, int out_size, void* d_ws, size_t ws_size,
                              hipStream_t stream) {
  (void)in_sizes; (void)n_in; (void)out_size;
  const float* X  = (const float*)d_in[0];   // sequence_output [64,512,1024]
  const int*   AM = (const int*)d_in[1];     // attention_mask  [64,512]
  const float* W  = (const float*)d_in[2];   // attention_weights [512,1024]
  float* Out = (float*)d_out;                // [64,512,1024]

  // ws layout: XhiC 64MiB | XloC 64MiB | Vc 64MiB | WhiC 1MiB | WloC 1MiB
  const size_t SZ_X = (size_t)Bn * Sn * Hn * sizeof(__bf16);  // 67108864
  const size_t SZ_W = (size_t)Ln * Hn * sizeof(__bf16);       // 1048576
  const size_t NEED = 3 * SZ_X + 2 * SZ_W;                    // 203423744

  if (d_ws != nullptr && ws_size >= NEED) {
    char* wsb = (char*)d_ws;
    __bf16* XhiC = (__bf16*)(wsb);
    __bf16* XloC = (__bf16*)(wsb + SZ_X);
    __bf16* Vc   = (__bf16*)(wsb + 2 * SZ_X);
    __bf16* WhiC = (__bf16*)(wsb + 3 * SZ_X);
    __bf16* WloC = (__bf16*)(wsb + 3 * SZ_X + SZ_W);
    prep_x<<<dim3(64 * 32 * 4), dim3(256), 0, stream>>>(X, XhiC, XloC, Vc);
    prep_w<<<dim3(256), dim3(256), 0, stream>>>(W, WhiC, WloC);
    mla_fused3<<<dim3(64 * 16), dim3(256), 0, stream>>>(XhiC, XloC, Vc, AM,
                                                        WhiC, WloC, Out);
  } else {
    mla_fused<<<dim3(64 * 16), dim3(256), 0, stream>>>(X, AM, W, Out);
  }
}

// Round 4
// 597.463 us; speedup vs baseline: 1.4138x; 1.0996x over previous
//
#include <hip/hip_runtime.h>

// MultiLabelAttention: out[b,l,h] = softmax_s(mask(W[l,:]·X[b,s,:])) · X[b,s,h]
// B=64 S=512 H=1024 L=512, fp32 in/out.
//
// R5: identical resubmit of R4 — the R4 bench died to container infra
// ("MI355X container failed twice"), not the kernel.
//
// R4: single-sweep, barrier-free GEMM1, register-direct loads.
//  prep_x: X fp32 -> XhiC/XloC [b][c=h/32][512 s][32 h] bf16 (natural slots)
//          and Vc [b][h/32][s/128][32 h][128 s] (V^T tiles). LDS transpose now
//          scalar-write / vector-read (was vector-write / scalar-read).
//  prep_w: W fp32 -> WhiC/WloC [c][512 l][32 h].
//  mla_fused4: ONE H-sweep computes all 512 scores into 64 VGPRs (sacc),
//          Q/K frags loaded straight from chunked global (1 KB/wave coalesced,
//          wave-private, NO LDS, NO barriers in GEMM1). Exact softmax (not
//          online): 2 barriers per block total. PV in one pass from Vc.
//  Numerics: same hi/lo split + 3-MFMA QK^T, bf16 PV; exact softmax is
//  mathematically identical to the online version.
//  Fallback: if ws too small, R1 kernel (raw inputs) unchanged.

typedef float  f4_t  __attribute__((ext_vector_type(4)));
typedef __bf16 bf8_t __attribute__((ext_vector_type(8)));
typedef __bf16 bf4_t __attribute__((ext_vector_type(4)));

constexpr int Sn = 512, Hn = 1024, Ln = 512, Bn = 64;
#define NEGINF (-1e9f)

__device__ __forceinline__ void split8(f4_t a, f4_t b, bf8_t& hi, bf8_t& lo) {
#pragma unroll
  for (int i = 0; i < 4; ++i) {
    float x = a[i];
    __bf16 h = (__bf16)x;
    hi[i] = h;
    lo[i] = (__bf16)(x - (float)h);
  }
#pragma unroll
  for (int i = 0; i < 4; ++i) {
    float x = b[i];
    __bf16 h = (__bf16)x;
    hi[4 + i] = h;
    lo[4 + i] = (__bf16)(x - (float)h);
  }
}

// ---------------------------------------------------------------------------
// prep_w: W[512,1024] -> WhiC/WloC [c][512 l][4 slot][8h]. 256 blk x 256 thr.
// dst index u*8 == (c*512 + l)*32 + slot*8 by construction.
// ---------------------------------------------------------------------------
__global__ void prep_w(const float* __restrict__ W, __bf16* __restrict__ WhiC,
                       __bf16* __restrict__ WloC) {
  const int u = blockIdx.x * 256 + threadIdx.x;  // 65536 units of 16 B
  const int c = u >> 11;
  const int l = (u >> 2) & 511;
  const int slot = u & 3;
  const float* src = W + (size_t)l * Hn + c * 32 + slot * 8;
  f4_t a = *(const f4_t*)src;
  f4_t b2 = *(const f4_t*)(src + 4);
  bf8_t hi, lo;
  split8(a, b2, hi, lo);
  *(bf8_t*)(WhiC + (size_t)u * 8) = hi;
  *(bf8_t*)(WloC + (size_t)u * 8) = lo;
}

// ---------------------------------------------------------------------------
// prep_x: per block, one [128 s][32 h] tile (b, chunk c, s-step st).
//  - write XhiC / XloC (chunked) with 16-B stores
//  - transpose via LDS: scalar WRITES into T[h][s], vector b128 READS out
// grid 8192 = 64 b x 32 c x 4 st, 256 thr.
// ---------------------------------------------------------------------------
__global__ __launch_bounds__(256)
void prep_x(const float* __restrict__ X, __bf16* __restrict__ XhiC,
            __bf16* __restrict__ XloC, __bf16* __restrict__ Vc) {
  __shared__ __bf16 T[32][136];  // transposed tile [h][s], 272-B rows (17x16B)
  const int bid = blockIdx.x;
  const int b  = bid >> 7;
  const int c  = (bid >> 2) & 31;
  const int st = bid & 3;
  const int s0 = st * 128;
  const int t  = threadIdx.x;

#pragma unroll
  for (int i = 0; i < 2; ++i) {
    const int u = i * 256 + t;        // 512 units of 16 B
    const int row = u >> 2;           // s within tile
    const int slot = u & 3;
    const float* src = X + ((size_t)(b * Sn + s0 + row)) * Hn + c * 32 + slot * 8;
    f4_t a = *(const f4_t*)src;
    f4_t b2 = *(const f4_t*)(src + 4);
    bf8_t hi, lo;
    split8(a, b2, hi, lo);
    const size_t o = (((size_t)(b * 32 + c) * 512) + s0 + row) * 32 + slot * 8;
    *(bf8_t*)(XhiC + o) = hi;
    *(bf8_t*)(XloC + o) = lo;
#pragma unroll
    for (int k = 0; k < 8; ++k) T[slot * 8 + k][row] = hi[k];
  }
  __syncthreads();
#pragma unroll
  for (int i = 0; i < 2; ++i) {
    const int u = i * 256 + t;        // 512 units of 16 B
    const int hr = u >> 4;            // h within chunk 0..31
    const int sg = (u & 15) * 8;      // s group of 8
    bf8_t o = *(const bf8_t*)&T[hr][sg];
    *(bf8_t*)(Vc + ((((size_t)b * 32 + c) * 4 + st) * 32 + hr) * 128 + sg) = o;
  }
}

// ---------------------------------------------------------------------------
// mla_fused4: single H-sweep, barrier-free GEMM1, exact softmax, one PV pass.
// ---------------------------------------------------------------------------
__global__ __launch_bounds__(256, 2)
void mla_fused4(const __bf16* __restrict__ XhiC, const __bf16* __restrict__ XloC,
                const __bf16* __restrict__ Vc, const int* __restrict__ AM,
                const __bf16* __restrict__ WhiC, const __bf16* __restrict__ WloC,
                float* __restrict__ Out) {
  // XCD-aware swizzle: batch b -> XCD b&7; the 16 l-tiles of a batch run
  // temporally adjacent on one XCD so its ~5 MB working set stays L2/L3-hot.
  const int i0 = blockIdx.x;
  const int xcd = i0 & 7, jj = i0 >> 3;
  const int b  = (jj >> 4) * 8 + xcd;
  const int l0 = (jj & 15) * 32;

  const int tid  = threadIdx.x;
  const int w    = tid >> 6;         // wave 0..3
  const int lane = tid & 63;
  const int n16  = lane & 15;
  const int quad = lane >> 4;

  __shared__ __bf16 fragP[32][520];  // 33.3 KB, full P row block (A-frag layout)
  __shared__ float  red[2][4][32];   // 1 KB

  const f4_t fzero = {0.f, 0.f, 0.f, 0.f};
  const f4_t fneg  = {NEGINF, NEGINF, NEGINF, NEGINF};

  const __bf16* XhiB = XhiC + (size_t)b * (32 * 512 * 32);
  const __bf16* XloB = XloC + (size_t)b * (32 * 512 * 32);
  const __bf16* VcB  = Vc   + (size_t)b * (32 * 4 * 32 * 128);

  // ---------------- GEMM1: all 512 scores in one H sweep ----------------
  // wave w owns s-cols {st*128 + w*32 + nt*16 + n16} for st in 0..3, nt in 0..1
  f4_t sacc[2][4][2];
#pragma unroll
  for (int mt = 0; mt < 2; ++mt)
#pragma unroll
    for (int st = 0; st < 4; ++st)
#pragma unroll
      for (int nt = 0; nt < 2; ++nt) sacc[mt][st][nt] = fzero;

  {
    const __bf16* qhB = WhiC + (size_t)(l0 + n16) * 32 + quad * 8;
    const __bf16* qlB = WloC + (size_t)(l0 + n16) * 32 + quad * 8;
    const __bf16* khB = XhiB + (size_t)(w * 32 + n16) * 32 + quad * 8;
    const __bf16* klB = XloB + (size_t)(w * 32 + n16) * 32 + quad * 8;

    for (int c = 0; c < 32; ++c) {
      const __bf16* qh = qhB + (size_t)c * 16384;
      const __bf16* ql = qlB + (size_t)c * 16384;
      const __bf16* kh = khB + (size_t)c * 16384;
      const __bf16* kl = klB + (size_t)c * 16384;
      bf8_t qh0 = *(const bf8_t*)(qh);
      bf8_t qh1 = *(const bf8_t*)(qh + 512);
      bf8_t ql0 = *(const bf8_t*)(ql);
      bf8_t ql1 = *(const bf8_t*)(ql + 512);
#pragma unroll
      for (int st = 0; st < 4; ++st) {
        bf8_t kh0 = *(const bf8_t*)(kh + st * 4096);
        bf8_t kh1 = *(const bf8_t*)(kh + st * 4096 + 512);
        bf8_t kl0 = *(const bf8_t*)(kl + st * 4096);
        bf8_t kl1 = *(const bf8_t*)(kl + st * 4096 + 512);
        f4_t cc;
        cc = sacc[0][st][0];
        cc = __builtin_amdgcn_mfma_f32_16x16x32_bf16(qh0, kh0, cc, 0, 0, 0);
        cc = __builtin_amdgcn_mfma_f32_16x16x32_bf16(qh0, kl0, cc, 0, 0, 0);
        cc = __builtin_amdgcn_mfma_f32_16x16x32_bf16(ql0, kh0, cc, 0, 0, 0);
        sacc[0][st][0] = cc;
        cc = sacc[0][st][1];
        cc = __builtin_amdgcn_mfma_f32_16x16x32_bf16(qh0, kh1, cc, 0, 0, 0);
        cc = __builtin_amdgcn_mfma_f32_16x16x32_bf16(qh0, kl1, cc, 0, 0, 0);
        cc = __builtin_amdgcn_mfma_f32_16x16x32_bf16(ql0, kh1, cc, 0, 0, 0);
        sacc[0][st][1] = cc;
        cc = sacc[1][st][0];
        cc = __builtin_amdgcn_mfma_f32_16x16x32_bf16(qh1, kh0, cc, 0, 0, 0);
        cc = __builtin_amdgcn_mfma_f32_16x16x32_bf16(qh1, kl0, cc, 0, 0, 0);
        cc = __builtin_amdgcn_mfma_f32_16x16x32_bf16(ql1, kh0, cc, 0, 0, 0);
        sacc[1][st][0] = cc;
        cc = sacc[1][st][1];
        cc = __builtin_amdgcn_mfma_f32_16x16x32_bf16(qh1, kh1, cc, 0, 0, 0);
        cc = __builtin_amdgcn_mfma_f32_16x16x32_bf16(qh1, kl1, cc, 0, 0, 0);
        cc = __builtin_amdgcn_mfma_f32_16x16x32_bf16(ql1, kh1, cc, 0, 0, 0);
        sacc[1][st][1] = cc;
      }
    }
  }

  // ---------------- mask ----------------
  {
    const int* mrow = AM + b * Sn + w * 32 + n16;
#pragma unroll
    for (int st = 0; st < 4; ++st)
#pragma unroll
      for (int nt = 0; nt < 2; ++nt) {
        int mk = mrow[st * 128 + nt * 16];
        if (!mk) { sacc[0][st][nt] = fneg; sacc[1][st][nt] = fneg; }
      }
  }

  // ---------------- exact softmax (2 barriers) ----------------
  float rmx[2][4];
#pragma unroll
  for (int mt = 0; mt < 2; ++mt)
#pragma unroll
    for (int r = 0; r < 4; ++r) {
      float v = -3e38f;
#pragma unroll
      for (int st = 0; st < 4; ++st)
        v = fmaxf(v, fmaxf(sacc[mt][st][0][r], sacc[mt][st][1][r]));
      v = fmaxf(v, __shfl_xor(v, 1));
      v = fmaxf(v, __shfl_xor(v, 2));
      v = fmaxf(v, __shfl_xor(v, 4));
      v = fmaxf(v, __shfl_xor(v, 8));
      rmx[mt][r] = v;
    }
  if (n16 == 0) {
#pragma unroll
    for (int mt = 0; mt < 2; ++mt)
#pragma unroll
      for (int r = 0; r < 4; ++r)
        red[0][w][mt * 16 + quad * 4 + r] = rmx[mt][r];
  }
  __syncthreads();  // barrier A

  float m_v[2][4], psum[2][4];
#pragma unroll
  for (int mt = 0; mt < 2; ++mt)
#pragma unroll
    for (int r = 0; r < 4; ++r) {
      const int row = mt * 16 + quad * 4 + r;
      m_v[mt][r] = fmaxf(fmaxf(red[0][0][row], red[0][1][row]),
                         fmaxf(red[0][2][row], red[0][3][row]));
      psum[mt][r] = 0.f;
    }

#pragma unroll
  for (int mt = 0; mt < 2; ++mt)
#pragma unroll
    for (int st = 0; st < 4; ++st)
#pragma unroll
      for (int nt = 0; nt < 2; ++nt)
#pragma unroll
        for (int r = 0; r < 4; ++r) {
          const int row = mt * 16 + quad * 4 + r;
          float p = __expf(sacc[mt][st][nt][r] - m_v[mt][r]);
          psum[mt][r] += p;
          fragP[row][st * 128 + w * 32 + nt * 16 + n16] = (__bf16)p;
        }

#pragma unroll
  for (int mt = 0; mt < 2; ++mt)
#pragma unroll
    for (int r = 0; r < 4; ++r) {
      float v = psum[mt][r];
      v += __shfl_xor(v, 1);
      v += __shfl_xor(v, 2);
      v += __shfl_xor(v, 4);
      v += __shfl_xor(v, 8);
      if (n16 == 0) red[1][w][mt * 16 + quad * 4 + r] = v;
    }
  __syncthreads();  // barrier B (also publishes fragP)

  float l_v[2][4];
#pragma unroll
  for (int mt = 0; mt < 2; ++mt)
#pragma unroll
    for (int r = 0; r < 4; ++r) {
      const int row = mt * 16 + quad * 4 + r;
      l_v[mt][r] = red[1][0][row] + red[1][1][row] + red[1][2][row] + red[1][3][row];
    }

  // ---------------- GEMM2: O = P[32,512] x V[512,1024], one pass ----------
  f4_t oacc[2][16];
#pragma unroll
  for (int mt = 0; mt < 2; ++mt)
#pragma unroll
    for (int nt = 0; nt < 16; ++nt) oacc[mt][nt] = fzero;

  for (int kc = 0; kc < 16; ++kc) {
    bf8_t pa0 = *(const bf8_t*)&fragP[n16][kc * 32 + quad * 8];
    bf8_t pa1 = *(const bf8_t*)&fragP[16 + n16][kc * 32 + quad * 8];
    const __bf16* vk = VcB + ((size_t)(kc >> 2)) * 4096 + (kc & 3) * 32 + quad * 8;
#pragma unroll
    for (int hc = 0; hc < 8; ++hc) {
      const __bf16* vt = vk + (size_t)(w * 8 + hc) * 16384;
      bf8_t vv0 = *(const bf8_t*)(vt + n16 * 128);
      bf8_t vv1 = *(const bf8_t*)(vt + (n16 + 16) * 128);
      oacc[0][hc * 2]     = __builtin_amdgcn_mfma_f32_16x16x32_bf16(
          pa0, vv0, oacc[0][hc * 2], 0, 0, 0);
      oacc[1][hc * 2]     = __builtin_amdgcn_mfma_f32_16x16x32_bf16(
          pa1, vv0, oacc[1][hc * 2], 0, 0, 0);
      oacc[0][hc * 2 + 1] = __builtin_amdgcn_mfma_f32_16x16x32_bf16(
          pa0, vv1, oacc[0][hc * 2 + 1], 0, 0, 0);
      oacc[1][hc * 2 + 1] = __builtin_amdgcn_mfma_f32_16x16x32_bf16(
          pa1, vv1, oacc[1][hc * 2 + 1], 0, 0, 0);
    }
  }

  // ---------------- epilogue: O /= l, store ----------------
  float* ob = Out + ((size_t)b * Ln + l0) * Hn;
#pragma unroll
  for (int mt = 0; mt < 2; ++mt)
#pragma unroll
    for (int r = 0; r < 4; ++r) {
      const int row = mt * 16 + quad * 4 + r;
      const float inv = 1.f / l_v[mt][r];
#pragma unroll
      for (int nt = 0; nt < 16; ++nt) {
        ob[(size_t)row * Hn + w * 256 + nt * 16 + n16] = oacc[mt][nt][r] * inv;
      }
    }
}

// ---------------------------------------------------------------------------
// R1 kernel, kept verbatim as fallback when ws is too small (raw inputs).
// ---------------------------------------------------------------------------
__global__ __launch_bounds__(256, 2)
void mla_fused(const float* __restrict__ X, const int* __restrict__ AM,
               const float* __restrict__ W, float* __restrict__ Out) {
  const int bl   = blockIdx.x;
  const int b    = bl >> 4;
  const int l0   = (bl & 15) * 32;
  const int tid  = threadIdx.x;
  const int w    = tid >> 6;
  const int lane = tid & 63;
  const int n16  = lane & 15;
  const int quad = lane >> 4;

  __shared__ __bf16 fragP[32][136];
  __shared__ __bf16 fragV[4][32][136];
  __shared__ float  red[2][4][32];

  const f4_t fzero = {0.f, 0.f, 0.f, 0.f};
  const f4_t fneg  = {NEGINF, NEGINF, NEGINF, NEGINF};

  f4_t oacc[2][16];
#pragma unroll
  for (int mt = 0; mt < 2; ++mt)
#pragma unroll
    for (int nt = 0; nt < 16; ++nt) oacc[mt][nt] = fzero;

  float m_pr[2][4], l_pr[2][4];
#pragma unroll
  for (int mt = 0; mt < 2; ++mt)
#pragma unroll
    for (int r = 0; r < 4; ++r) { m_pr[mt][r] = -3e38f; l_pr[mt][r] = 0.f; }

  const float* Xb = X + (size_t)b * Sn * Hn;

  for (int step = 0; step < 4; ++step) {
    const int s0 = step * 128;

    f4_t sacc[2][2];
    sacc[0][0] = fzero; sacc[0][1] = fzero; sacc[1][0] = fzero; sacc[1][1] = fzero;

    const float* q0 = W  + (size_t)(l0 + n16) * Hn + quad * 8;
    const float* q1 = q0 + 16 * Hn;
    const float* k0 = Xb + (size_t)(s0 + w * 32 + n16) * Hn + quad * 8;
    const float* k1 = k0 + 16 * Hn;

    for (int hk = 0; hk < Hn; hk += 32) {
      bf8_t qh[2], ql[2], kh[2], kl[2];
      {
        f4_t a0 = *(const f4_t*)(q0 + hk);
        f4_t a1 = *(const f4_t*)(q0 + hk + 4);
        f4_t a2 = *(const f4_t*)(q1 + hk);
        f4_t a3 = *(const f4_t*)(q1 + hk + 4);
        f4_t c0 = *(const f4_t*)(k0 + hk);
        f4_t c1 = *(const f4_t*)(k0 + hk + 4);
        f4_t c2 = *(const f4_t*)(k1 + hk);
        f4_t c3 = *(const f4_t*)(k1 + hk + 4);
        split8(a0, a1, qh[0], ql[0]);
        split8(a2, a3, qh[1], ql[1]);
        split8(c0, c1, kh[0], kl[0]);
        split8(c2, c3, kh[1], kl[1]);
      }
#pragma unroll
      for (int mt = 0; mt < 2; ++mt)
#pragma unroll
        for (int nt = 0; nt < 2; ++nt) {
          f4_t c = sacc[mt][nt];
          c = __builtin_amdgcn_mfma_f32_16x16x32_bf16(qh[mt], kh[nt], c, 0, 0, 0);
          c = __builtin_amdgcn_mfma_f32_16x16x32_bf16(qh[mt], kl[nt], c, 0, 0, 0);
          c = __builtin_amdgcn_mfma_f32_16x16x32_bf16(ql[mt], kh[nt], c, 0, 0, 0);
          sacc[mt][nt] = c;
        }
    }

    {
      const int* mrow = AM + b * Sn + s0 + w * 32 + n16;
      int mk0 = mrow[0];
      int mk1 = mrow[16];
      if (!mk0) { sacc[0][0] = fneg; sacc[1][0] = fneg; }
      if (!mk1) { sacc[0][1] = fneg; sacc[1][1] = fneg; }
    }

    float rmx[2][4];
#pragma unroll
    for (int mt = 0; mt < 2; ++mt)
#pragma unroll
      for (int r = 0; r < 4; ++r) {
        float v = fmaxf(sacc[mt][0][r], sacc[mt][1][r]);
        v = fmaxf(v, __shfl_xor(v, 1));
        v = fmaxf(v, __shfl_xor(v, 2));
        v = fmaxf(v, __shfl_xor(v, 4));
        v = fmaxf(v, __shfl_xor(v, 8));
        rmx[mt][r] = v;
      }
    if (n16 == 0) {
#pragma unroll
      for (int mt = 0; mt < 2; ++mt)
#pragma unroll
        for (int r = 0; r < 4; ++r)
          red[0][w][mt * 16 + quad * 4 + r] = rmx[mt][r];
    }
    __syncthreads();

    float al[2][4], psum[2][4];
#pragma unroll
    for (int mt = 0; mt < 2; ++mt)
#pragma unroll
      for (int r = 0; r < 4; ++r) {
        const int row = mt * 16 + quad * 4 + r;
        float bm = fmaxf(fmaxf(red[0][0][row], red[0][1][row]),
                         fmaxf(red[0][2][row], red[0][3][row]));
        float mn = fmaxf(m_pr[mt][r], bm);
        al[mt][r] = __expf(m_pr[mt][r] - mn);
        m_pr[mt][r] = mn;
        psum[mt][r] = 0.f;
      }

#pragma unroll
    for (int mt = 0; mt < 2; ++mt)
#pragma unroll
      for (int nt = 0; nt < 2; ++nt)
#pragma unroll
        for (int r = 0; r < 4; ++r) {
          const int row = mt * 16 + quad * 4 + r;
          float p = __expf(sacc[mt][nt][r] - m_pr[mt][r]);
          psum[mt][r] += p;
          fragP[row][w * 32 + nt * 16 + n16] = (__bf16)p;
        }

#pragma unroll
    for (int mt = 0; mt < 2; ++mt)
#pragma unroll
      for (int r = 0; r < 4; ++r) {
        float v = psum[mt][r];
        v += __shfl_xor(v, 1);
        v += __shfl_xor(v, 2);
        v += __shfl_xor(v, 4);
        v += __shfl_xor(v, 8);
        if (n16 == 0) red[1][w][mt * 16 + quad * 4 + r] = v;
      }
    __syncthreads();

#pragma unroll
    for (int mt = 0; mt < 2; ++mt)
#pragma unroll
      for (int r = 0; r < 4; ++r) {
        const int row = mt * 16 + quad * 4 + r;
        float bs = red[1][0][row] + red[1][1][row] + red[1][2][row] + red[1][3][row];
        l_pr[mt][r] = l_pr[mt][r] * al[mt][r] + bs;
      }
#pragma unroll
    for (int mt = 0; mt < 2; ++mt)
#pragma unroll
      for (int nt = 0; nt < 16; ++nt)
#pragma unroll
        for (int r = 0; r < 4; ++r) oacc[mt][nt][r] *= al[mt][r];

    const int colg = lane & 7;
    const int sg   = lane >> 3;
    for (int hc = 0; hc < 8; ++hc) {
      const int h0 = w * 256 + hc * 32;
      const float* vsrc = Xb + (size_t)(s0 + sg * 4) * Hn + h0 + colg * 4;
#pragma unroll
      for (int it = 0; it < 4; ++it) {
        const float* p = vsrc + (size_t)(it * 32) * Hn;
        f4_t r0v = *(const f4_t*)(p);
        f4_t r1v = *(const f4_t*)(p + Hn);
        f4_t r2v = *(const f4_t*)(p + 2 * Hn);
        f4_t r3v = *(const f4_t*)(p + 3 * Hn);
        const int si = it * 32 + sg * 4;
#pragma unroll
        for (int cix = 0; cix < 4; ++cix) {
          bf4_t v;
          v[0] = (__bf16)r0v[cix];
          v[1] = (__bf16)r1v[cix];
          v[2] = (__bf16)r2v[cix];
          v[3] = (__bf16)r3v[cix];
          *(bf4_t*)&fragV[w][colg * 4 + cix][si] = v;
        }
      }
#pragma unroll
      for (int kk = 0; kk < 4; ++kk) {
        bf8_t pa0 = *(const bf8_t*)&fragP[n16][kk * 32 + quad * 8];
        bf8_t pa1 = *(const bf8_t*)&fragP[16 + n16][kk * 32 + quad * 8];
#pragma unroll
        for (int ntl = 0; ntl < 2; ++ntl) {
          bf8_t vv = *(const bf8_t*)&fragV[w][ntl * 16 + n16][kk * 32 + quad * 8];
          oacc[0][hc * 2 + ntl] =
              __builtin_amdgcn_mfma_f32_16x16x32_bf16(pa0, vv, oacc[0][hc * 2 + ntl], 0, 0, 0);
          oacc[1][hc * 2 + ntl] =
              __builtin_amdgcn_mfma_f32_16x16x32_bf16(pa1, vv, oacc[1][hc * 2 + ntl], 0, 0, 0);
        }
      }
    }
  }

  float* ob = Out + ((size_t)b * Ln + l0) * Hn;
#pragma unroll
  for (int mt = 0; mt < 2; ++mt)
#pragma unroll
    for (int r = 0; r < 4; ++r) {
      const int row = mt * 16 + quad * 4 + r;
      const float inv = 1.f / l_pr[mt][r];
#pragma unroll
      for (int nt = 0; nt < 16; ++nt) {
        ob[(size_t)row * Hn + w * 256 + nt * 16 + n16] = oacc[mt][nt][r] * inv;
      }
    }
}

extern "C" void kernel_launch(void* const* d_in, const int* in_sizes, int n_in,
                              void* d_out, int out_size, void* d_ws, size_t ws_size,
                              hipStream_t stream) {
  (void)in_sizes; (void)n_in; (void)out_size;
  const float* X  = (const float*)d_in[0];   // sequence_output [64,512,1024]
  const int*   AM = (const int*)d_in[1];     // attention_mask  [64,512]
  const float* W  = (const float*)d_in[2];   // attention_weights [512,1024]
  float* Out = (float*)d_out;                // [64,512,1024]

  // ws layout: XhiC 64MiB | XloC 64MiB | Vc 64MiB | WhiC 1MiB | WloC 1MiB
  const size_t SZ_X = (size_t)Bn * Sn * Hn * sizeof(__bf16);  // 67108864
  const size_t SZ_W = (size_t)Ln * Hn * sizeof(__bf16);       // 1048576
  const size_t NEED = 3 * SZ_X + 2 * SZ_W;                    // 203423744

  if (d_ws != nullptr && ws_size >= NEED) {
    char* wsb = (char*)d_ws;
    __bf16* XhiC = (__bf16*)(wsb);
    __bf16* XloC = (__bf16*)(wsb + SZ_X);
    __bf16* Vc   = (__bf16*)(wsb + 2 * SZ_X);
    __bf16* WhiC = (__bf16*)(wsb + 3 * SZ_X);
    __bf16* WloC = (__bf16*)(wsb + 3 * SZ_X + SZ_W);
    prep_x<<<dim3(64 * 32 * 4), dim3(256), 0, stream>>>(X, XhiC, XloC, Vc);
    prep_w<<<dim3(256), dim3(256), 0, stream>>>(W, WhiC, WloC);
    mla_fused4<<<dim3(64 * 16), dim3(256), 0, stream>>>(XhiC, XloC, Vc, AM,
                                                        WhiC, WloC, Out);
  } else {
    mla_fused<<<dim3(64 * 16), dim3(256), 0, stream>>>(X, AM, W, Out);
  }
}

// Round 5
// 515.864 us; speedup vs baseline: 1.6374x; 1.1582x over previous
//
#include <hip/hip_runtime.h>

// MultiLabelAttention: out[b,l,h] = softmax_s(mask(W[l,:]·X[b,s,:])) · X[b,s,h]
// B=64 S=512 H=1024 L=512, fp32 in/out.
//
// R6: two-kernel split + explicit register double-buffering.
//  prep_x: X fp32 -> XhiC/XloC [b][c=h/32][512 s][32 h] bf16 and
//          Vc2 [b][sc=s/32][1024 h][32 s] (V^T, s-chunked). Grid-stride 2048.
//  prep_w: W fp32 -> WhiC/WloC [c][512 l][32 h].
//  mla_qk: per block 64 l-rows (8 blocks/batch, 512 thr, 8 waves x 64 s).
//          A/B double-buffered register pipeline (16 loads in flight under
//          48 MFMAs). Exact softmax; P written register->global (chunked
//          Pws[b][s/32][512 l][32 s] bf16); row sums to Lws. LDS = 4 KB.
//  mla_pv: P[512,512] x V[512,1024] per batch; 128x128 tiles, 4 waves,
//          oacc 64 regs -> 3 blocks/CU; A/B pipelined 1-KB frag loads.
//  Numerics identical to R5 (same split, same MFMA order, bf16 PV, exact SM).
//  Tiers: ws >= 227 MiB full split; >= 194 MiB R5 fused4 (Vc2-adapted); else R1.

typedef float  f4_t  __attribute__((ext_vector_type(4)));
typedef __bf16 bf8_t __attribute__((ext_vector_type(8)));
typedef __bf16 bf4_t __attribute__((ext_vector_type(4)));

constexpr int Sn = 512, Hn = 1024, Ln = 512, Bn = 64;
#define NEGINF (-1e9f)

__device__ __forceinline__ void split8(f4_t a, f4_t b, bf8_t& hi, bf8_t& lo) {
#pragma unroll
  for (int i = 0; i < 4; ++i) {
    float x = a[i];
    __bf16 h = (__bf16)x;
    hi[i] = h;
    lo[i] = (__bf16)(x - (float)h);
  }
#pragma unroll
  for (int i = 0; i < 4; ++i) {
    float x = b[i];
    __bf16 h = (__bf16)x;
    hi[4 + i] = h;
    lo[4 + i] = (__bf16)(x - (float)h);
  }
}

// ---------------------------------------------------------------------------
// prep_w: W[512,1024] -> WhiC/WloC [c][512 l][32 h]. 256 blk x 256 thr.
// ---------------------------------------------------------------------------
__global__ void prep_w(const float* __restrict__ W, __bf16* __restrict__ WhiC,
                       __bf16* __restrict__ WloC) {
  const int u = blockIdx.x * 256 + threadIdx.x;  // 65536 units of 16 B
  const int c = u >> 11;
  const int l = (u >> 2) & 511;
  const int slot = u & 3;
  const float* src = W + (size_t)l * Hn + c * 32 + slot * 8;
  f4_t a = *(const f4_t*)src;
  f4_t b2 = *(const f4_t*)(src + 4);
  bf8_t hi, lo;
  split8(a, b2, hi, lo);
  *(bf8_t*)(WhiC + (size_t)u * 8) = hi;
  *(bf8_t*)(WloC + (size_t)u * 8) = lo;
}

// ---------------------------------------------------------------------------
// prep_x: per tile, one [128 s][32 h] block of X (b, chunk c, s-step st).
//  - write XhiC / XloC (chunked) with 16-B stores
//  - transpose via LDS (scalar write / vector read) -> Vc2 [sc][h][32 s]
// 2048 blocks x 256 thr, grid-stride over 8192 tiles.
// ---------------------------------------------------------------------------
__global__ __launch_bounds__(256)
void prep_x(const float* __restrict__ X, __bf16* __restrict__ XhiC,
            __bf16* __restrict__ XloC, __bf16* __restrict__ Vc2) {
  __shared__ __bf16 T[32][136];  // [h][s] tile, 272-B rows (17x16B, aligned)
  const int t = threadIdx.x;

  for (int tile = blockIdx.x; tile < 8192; tile += 2048) {
    const int b  = tile >> 7;
    const int c  = (tile >> 2) & 31;
    const int st = tile & 3;
    const int s0 = st * 128;

#pragma unroll
    for (int i = 0; i < 2; ++i) {
      const int u = i * 256 + t;        // 512 units of 16 B (out)
      const int row = u >> 2;           // s within tile
      const int slot = u & 3;
      const float* src = X + ((size_t)(b * Sn + s0 + row)) * Hn + c * 32 + slot * 8;
      f4_t a = *(const f4_t*)src;
      f4_t b2 = *(const f4_t*)(src + 4);
      bf8_t hi, lo;
      split8(a, b2, hi, lo);
      const size_t o = (((size_t)(b * 32 + c) * 512) + s0 + row) * 32 + slot * 8;
      *(bf8_t*)(XhiC + o) = hi;
      *(bf8_t*)(XloC + o) = lo;
#pragma unroll
      for (int k = 0; k < 8; ++k) T[slot * 8 + k][row] = hi[k];
    }
    __syncthreads();
#pragma unroll
    for (int i = 0; i < 2; ++i) {
      const int u = i * 256 + t;        // 512 units of 16 B
      const int hr = u >> 4;            // h within chunk 0..31
      const int sg = u & 15;            // s group of 8 within 128
      bf8_t o = *(const bf8_t*)&T[hr][sg * 8];
      const int sc = st * 4 + (sg >> 2);
      const int si = (sg & 3) * 8;
      *(bf8_t*)(Vc2 + (((size_t)(b * 16 + sc)) * 1024 + c * 32 + hr) * 32 + si) = o;
    }
    __syncthreads();  // T reused next tile
  }
}

// ---------------------------------------------------------------------------
// mla_qk: QK^T + exact softmax for 64 l-rows. 512 thr (8 waves x 64 s).
// Writes Pws [b][sc=s/32][512 l][32 s] bf16 and Lws [b][512 l] f32.
// ---------------------------------------------------------------------------
struct QKFrags {
  bf8_t qh[4], ql[4], kh[4], kl[4];
};

#define QK_LOAD(F, cc_)                                                        \
  {                                                                            \
    _Pragma("unroll") for (int mt = 0; mt < 4; ++mt) {                         \
      (F).qh[mt] = *(const bf8_t*)(qhB + (size_t)(cc_)*16384 + mt * 512);      \
      (F).ql[mt] = *(const bf8_t*)(qlB + (size_t)(cc_)*16384 + mt * 512);      \
    }                                                                          \
    _Pragma("unroll") for (int nt = 0; nt < 4; ++nt) {                         \
      (F).kh[nt] = *(const bf8_t*)(khB + (size_t)(cc_)*16384 + nt * 512);      \
      (F).kl[nt] = *(const bf8_t*)(klB + (size_t)(cc_)*16384 + nt * 512);      \
    }                                                                          \
  }

#define QK_MFMA(F)                                                             \
  {                                                                            \
    _Pragma("unroll") for (int mt = 0; mt < 4; ++mt)                           \
        _Pragma("unroll") for (int nt = 0; nt < 4; ++nt) {                     \
      f4_t cc = sacc[mt][nt];                                                  \
      cc = __builtin_amdgcn_mfma_f32_16x16x32_bf16((F).qh[mt], (F).kh[nt], cc, \
                                                   0, 0, 0);                   \
      cc = __builtin_amdgcn_mfma_f32_16x16x32_bf16((F).qh[mt], (F).kl[nt], cc, \
                                                   0, 0, 0);                   \
      cc = __builtin_amdgcn_mfma_f32_16x16x32_bf16((F).ql[mt], (F).kh[nt], cc, \
                                                   0, 0, 0);                   \
      sacc[mt][nt] = cc;                                                       \
    }                                                                          \
  }

__global__ __launch_bounds__(512, 2)
void mla_qk(const __bf16* __restrict__ XhiC, const __bf16* __restrict__ XloC,
            const int* __restrict__ AM, const __bf16* __restrict__ WhiC,
            const __bf16* __restrict__ WloC, __bf16* __restrict__ Pws,
            float* __restrict__ Lws) {
  // grid 512 = 64 b x 8 l-tiles; same-batch blocks on one XCD.
  const int i0 = blockIdx.x;
  const int xcd = i0 & 7, jj = i0 >> 3;      // jj 0..63
  const int b  = (jj >> 3) * 8 + xcd;
  const int l0 = (jj & 7) * 64;

  const int tid  = threadIdx.x;
  const int w    = tid >> 6;                 // wave 0..7 -> s-range w*64
  const int lane = tid & 63;
  const int n16  = lane & 15;
  const int quad = lane >> 4;

  __shared__ float red0[64][8];
  __shared__ float red1[64][8];

  const f4_t fzero = {0.f, 0.f, 0.f, 0.f};
  const f4_t fneg  = {NEGINF, NEGINF, NEGINF, NEGINF};

  f4_t sacc[4][4];
#pragma unroll
  for (int mt = 0; mt < 4; ++mt)
#pragma unroll
    for (int nt = 0; nt < 4; ++nt) sacc[mt][nt] = fzero;

  const __bf16* qhB = WhiC + (size_t)(l0 + n16) * 32 + quad * 8;
  const __bf16* qlB = WloC + (size_t)(l0 + n16) * 32 + quad * 8;
  const __bf16* khB = XhiC + (size_t)b * (32 * 512 * 32) +
                      (size_t)(w * 64 + n16) * 32 + quad * 8;
  const __bf16* klB = XloC + (size_t)b * (32 * 512 * 32) +
                      (size_t)(w * 64 + n16) * 32 + quad * 8;

  // -------- GEMM1: 2-deep register-pipelined H sweep, no LDS, no barriers --
  {
    QKFrags fA, fB;
    QK_LOAD(fA, 0);
    for (int c = 0; c < 32; c += 2) {
      QK_LOAD(fB, c + 1);
      QK_MFMA(fA);
      if (c + 2 < 32) QK_LOAD(fA, c + 2);
      QK_MFMA(fB);
    }
  }

  // -------- mask --------
  {
    const int* mrow = AM + b * Sn + w * 64 + n16;
#pragma unroll
    for (int nt = 0; nt < 4; ++nt) {
      int mk = mrow[nt * 16];
      if (!mk) {
#pragma unroll
        for (int mt = 0; mt < 4; ++mt) sacc[mt][nt] = fneg;
      }
    }
  }

  // -------- exact softmax (2 barriers) --------
#pragma unroll
  for (int mt = 0; mt < 4; ++mt)
#pragma unroll
    for (int r = 0; r < 4; ++r) {
      float v = fmaxf(fmaxf(sacc[mt][0][r], sacc[mt][1][r]),
                      fmaxf(sacc[mt][2][r], sacc[mt][3][r]));
      v = fmaxf(v, __shfl_xor(v, 1));
      v = fmaxf(v, __shfl_xor(v, 2));
      v = fmaxf(v, __shfl_xor(v, 4));
      v = fmaxf(v, __shfl_xor(v, 8));
      if (n16 == 0) red0[mt * 16 + quad * 4 + r][w] = v;
    }
  __syncthreads();  // barrier A

  float m_v[4][4], psum[4][4];
#pragma unroll
  for (int mt = 0; mt < 4; ++mt)
#pragma unroll
    for (int r = 0; r < 4; ++r) {
      const int row = mt * 16 + quad * 4 + r;
      f4_t a = *(const f4_t*)&red0[row][0];
      f4_t c = *(const f4_t*)&red0[row][4];
      m_v[mt][r] = fmaxf(fmaxf(fmaxf(a[0], a[1]), fmaxf(a[2], a[3])),
                         fmaxf(fmaxf(c[0], c[1]), fmaxf(c[2], c[3])));
      psum[mt][r] = 0.f;
    }

  // p = exp(s-m): accumulate row sums + store P straight to global (chunked)
  {
    __bf16* pb0 = Pws + ((size_t)(b * 16 + 2 * w) * 512 + l0 + quad * 4) * 32 + n16;
    __bf16* pb1 = pb0 + 512 * 32;  // second s-chunk of this wave
#pragma unroll
    for (int mt = 0; mt < 4; ++mt)
#pragma unroll
      for (int nt = 0; nt < 4; ++nt)
#pragma unroll
        for (int r = 0; r < 4; ++r) {
          float p = __expf(sacc[mt][nt][r] - m_v[mt][r]);
          psum[mt][r] += p;
          __bf16* dst = (nt < 2) ? pb0 : pb1;
          dst[(mt * 16 + r) * 32 + (nt & 1) * 16] = (__bf16)p;
        }
  }

#pragma unroll
  for (int mt = 0; mt < 4; ++mt)
#pragma unroll
    for (int r = 0; r < 4; ++r) {
      float v = psum[mt][r];
      v += __shfl_xor(v, 1);
      v += __shfl_xor(v, 2);
      v += __shfl_xor(v, 4);
      v += __shfl_xor(v, 8);
      if (n16 == 0) red1[mt * 16 + quad * 4 + r][w] = v;
    }
  __syncthreads();  // barrier B

  if (w == 0 && n16 == 0) {
#pragma unroll
    for (int mt = 0; mt < 4; ++mt)
#pragma unroll
      for (int r = 0; r < 4; ++r) {
        const int row = mt * 16 + quad * 4 + r;
        f4_t a = *(const f4_t*)&red1[row][0];
        f4_t c = *(const f4_t*)&red1[row][4];
        Lws[b * Ln + l0 + row] =
            (a[0] + a[1] + a[2] + a[3]) + (c[0] + c[1] + c[2] + c[3]);
      }
  }
}

// ---------------------------------------------------------------------------
// mla_pv: O = (P x V) / l. 256 thr (2x2 waves of 64x64), 128x128 block tile.
// ---------------------------------------------------------------------------
struct PVFrags {
  bf8_t pa[4], vv[4];
};

#define PV_LOAD(F, kk_)                                                        \
  {                                                                            \
    _Pragma("unroll") for (int mt = 0; mt < 4; ++mt)(F).pa[mt] =               \
        *(const bf8_t*)(paB + (size_t)(kk_)*16384 + mt * 512);                 \
    _Pragma("unroll") for (int nt = 0; nt < 4; ++nt)(F).vv[nt] =               \
        *(const bf8_t*)(vvB + (size_t)(kk_)*32768 + nt * 512);                 \
  }

#define PV_MFMA(F)                                                             \
  {                                                                            \
    _Pragma("unroll") for (int mt = 0; mt < 4; ++mt)                           \
        _Pragma("unroll") for (int nt = 0; nt < 4; ++nt) oacc[mt][nt] =        \
        __builtin_amdgcn_mfma_f32_16x16x32_bf16((F).pa[mt], (F).vv[nt],        \
                                                oacc[mt][nt], 0, 0, 0);        \
  }

__global__ __launch_bounds__(256, 3)
void mla_pv(const __bf16* __restrict__ Pws, const __bf16* __restrict__ Vc2,
            const float* __restrict__ Lws, float* __restrict__ Out) {
  // grid 2048 = 64 b x (4 lt x 8 ht); same-batch blocks on one XCD.
  const int i0 = blockIdx.x;
  const int xcd = i0 & 7, jj = i0 >> 3;      // jj 0..255
  const int b   = (jj >> 5) * 8 + xcd;
  const int lt  = (jj >> 3) & 3;
  const int ht  = jj & 7;

  const int tid  = threadIdx.x;
  const int w    = tid >> 6;
  const int wm   = w >> 1, wn = w & 1;
  const int lane = tid & 63;
  const int n16  = lane & 15;
  const int quad = lane >> 4;

  const int l0 = lt * 128 + wm * 64;
  const int h0 = ht * 128 + wn * 64;

  const f4_t fzero = {0.f, 0.f, 0.f, 0.f};
  f4_t oacc[4][4];
#pragma unroll
  for (int mt = 0; mt < 4; ++mt)
#pragma unroll
    for (int nt = 0; nt < 4; ++nt) oacc[mt][nt] = fzero;

  const __bf16* paB = Pws + ((size_t)(b * 16) * 512 + l0 + n16) * 32 + quad * 8;
  const __bf16* vvB = Vc2 + ((size_t)(b * 16) * 1024 + h0 + n16) * 32 + quad * 8;

  {
    PVFrags fA, fB;
    PV_LOAD(fA, 0);
    for (int kc = 0; kc < 16; kc += 2) {
      PV_LOAD(fB, kc + 1);
      PV_MFMA(fA);
      if (kc + 2 < 16) PV_LOAD(fA, kc + 2);
      PV_MFMA(fB);
    }
  }

  // epilogue: divide by row sums, store
  const float* lrow = Lws + b * Ln + l0 + quad * 4;
  float* ob = Out + ((size_t)b * Ln + l0 + quad * 4) * Hn + h0 + n16;
#pragma unroll
  for (int mt = 0; mt < 4; ++mt)
#pragma unroll
    for (int r = 0; r < 4; ++r) {
      const float inv = 1.f / lrow[mt * 16 + r];
      float* orow = ob + (size_t)(mt * 16 + r) * Hn;
#pragma unroll
      for (int nt = 0; nt < 4; ++nt) {
        orow[nt * 16] = oacc[mt][nt][r] * inv;
      }
    }
}

// ---------------------------------------------------------------------------
// mla_fused4 (R5 kernel, Vc2-adapted): mid-tier fallback.
// ---------------------------------------------------------------------------
__global__ __launch_bounds__(256, 2)
void mla_fused4(const __bf16* __restrict__ XhiC, const __bf16* __restrict__ XloC,
                const __bf16* __restrict__ Vc2, const int* __restrict__ AM,
                const __bf16* __restrict__ WhiC, const __bf16* __restrict__ WloC,
                float* __restrict__ Out) {
  const int i0 = blockIdx.x;
  const int xcd = i0 & 7, jj = i0 >> 3;
  const int b  = (jj >> 4) * 8 + xcd;
  const int l0 = (jj & 15) * 32;

  const int tid  = threadIdx.x;
  const int w    = tid >> 6;
  const int lane = tid & 63;
  const int n16  = lane & 15;
  const int quad = lane >> 4;

  __shared__ __bf16 fragP[32][520];
  __shared__ float  red[2][4][32];

  const f4_t fzero = {0.f, 0.f, 0.f, 0.f};
  const f4_t fneg  = {NEGINF, NEGINF, NEGINF, NEGINF};

  const __bf16* XhiB = XhiC + (size_t)b * (32 * 512 * 32);
  const __bf16* XloB = XloC + (size_t)b * (32 * 512 * 32);
  const __bf16* Vc2B = Vc2 + (size_t)b * (16 * 1024 * 32);

  f4_t sacc[2][4][2];
#pragma unroll
  for (int mt = 0; mt < 2; ++mt)
#pragma unroll
    for (int st = 0; st < 4; ++st)
#pragma unroll
      for (int nt = 0; nt < 2; ++nt) sacc[mt][st][nt] = fzero;

  {
    const __bf16* qhB = WhiC + (size_t)(l0 + n16) * 32 + quad * 8;
    const __bf16* qlB = WloC + (size_t)(l0 + n16) * 32 + quad * 8;
    const __bf16* khB = XhiB + (size_t)(w * 32 + n16) * 32 + quad * 8;
    const __bf16* klB = XloB + (size_t)(w * 32 + n16) * 32 + quad * 8;

    for (int c = 0; c < 32; ++c) {
      const __bf16* qh = qhB + (size_t)c * 16384;
      const __bf16* ql = qlB + (size_t)c * 16384;
      const __bf16* kh = khB + (size_t)c * 16384;
      const __bf16* kl = klB + (size_t)c * 16384;
      bf8_t qh0 = *(const bf8_t*)(qh);
      bf8_t qh1 = *(const bf8_t*)(qh + 512);
      bf8_t ql0 = *(const bf8_t*)(ql);
      bf8_t ql1 = *(const bf8_t*)(ql + 512);
#pragma unroll
      for (int st = 0; st < 4; ++st) {
        bf8_t kh0 = *(const bf8_t*)(kh + st * 4096);
        bf8_t kh1 = *(const bf8_t*)(kh + st * 4096 + 512);
        bf8_t kl0 = *(const bf8_t*)(kl + st * 4096);
        bf8_t kl1 = *(const bf8_t*)(kl + st * 4096 + 512);
        f4_t cc;
        cc = sacc[0][st][0];
        cc = __builtin_amdgcn_mfma_f32_16x16x32_bf16(qh0, kh0, cc, 0, 0, 0);
        cc = __builtin_amdgcn_mfma_f32_16x16x32_bf16(qh0, kl0, cc, 0, 0, 0);
        cc = __builtin_amdgcn_mfma_f32_16x16x32_bf16(ql0, kh0, cc, 0, 0, 0);
        sacc[0][st][0] = cc;
        cc = sacc[0][st][1];
        cc = __builtin_amdgcn_mfma_f32_16x16x32_bf16(qh0, kh1, cc, 0, 0, 0);
        cc = __builtin_amdgcn_mfma_f32_16x16x32_bf16(qh0, kl1, cc, 0, 0, 0);
        cc = __builtin_amdgcn_mfma_f32_16x16x32_bf16(ql0, kh1, cc, 0, 0, 0);
        sacc[0][st][1] = cc;
        cc = sacc[1][st][0];
        cc = __builtin_amdgcn_mfma_f32_16x16x32_bf16(qh1, kh0, cc, 0, 0, 0);
        cc = __builtin_amdgcn_mfma_f32_16x16x32_bf16(qh1, kl0, cc, 0, 0, 0);
        cc = __builtin_amdgcn_mfma_f32_16x16x32_bf16(ql1, kh0, cc, 0, 0, 0);
        sacc[1][st][0] = cc;
        cc = sacc[1][st][1];
        cc = __builtin_amdgcn_mfma_f32_16x16x32_bf16(qh1, kh1, cc, 0, 0, 0);
        cc = __builtin_amdgcn_mfma_f32_16x16x32_bf16(qh1, kl1, cc, 0, 0, 0);
        cc = __builtin_amdgcn_mfma_f32_16x16x32_bf16(ql1, kh1, cc, 0, 0, 0);
        sacc[1][st][1] = cc;
      }
    }
  }

  {
    const int* mrow = AM + b * Sn + w * 32 + n16;
#pragma unroll
    for (int st = 0; st < 4; ++st)
#pragma unroll
      for (int nt = 0; nt < 2; ++nt) {
        int mk = mrow[st * 128 + nt * 16];
        if (!mk) { sacc[0][st][nt] = fneg; sacc[1][st][nt] = fneg; }
      }
  }

  float rmx[2][4];
#pragma unroll
  for (int mt = 0; mt < 2; ++mt)
#pragma unroll
    for (int r = 0; r < 4; ++r) {
      float v = -3e38f;
#pragma unroll
      for (int st = 0; st < 4; ++st)
        v = fmaxf(v, fmaxf(sacc[mt][st][0][r], sacc[mt][st][1][r]));
      v = fmaxf(v, __shfl_xor(v, 1));
      v = fmaxf(v, __shfl_xor(v, 2));
      v = fmaxf(v, __shfl_xor(v, 4));
      v = fmaxf(v, __shfl_xor(v, 8));
      rmx[mt][r] = v;
    }
  if (n16 == 0) {
#pragma unroll
    for (int mt = 0; mt < 2; ++mt)
#pragma unroll
      for (int r = 0; r < 4; ++r)
        red[0][w][mt * 16 + quad * 4 + r] = rmx[mt][r];
  }
  __syncthreads();

  float m_v[2][4], psum[2][4];
#pragma unroll
  for (int mt = 0; mt < 2; ++mt)
#pragma unroll
    for (int r = 0; r < 4; ++r) {
      const int row = mt * 16 + quad * 4 + r;
      m_v[mt][r] = fmaxf(fmaxf(red[0][0][row], red[0][1][row]),
                         fmaxf(red[0][2][row], red[0][3][row]));
      psum[mt][r] = 0.f;
    }

#pragma unroll
  for (int mt = 0; mt < 2; ++mt)
#pragma unroll
    for (int st = 0; st < 4; ++st)
#pragma unroll
      for (int nt = 0; nt < 2; ++nt)
#pragma unroll
        for (int r = 0; r < 4; ++r) {
          const int row = mt * 16 + quad * 4 + r;
          float p = __expf(sacc[mt][st][nt][r] - m_v[mt][r]);
          psum[mt][r] += p;
          fragP[row][st * 128 + w * 32 + nt * 16 + n16] = (__bf16)p;
        }

#pragma unroll
  for (int mt = 0; mt < 2; ++mt)
#pragma unroll
    for (int r = 0; r < 4; ++r) {
      float v = psum[mt][r];
      v += __shfl_xor(v, 1);
      v += __shfl_xor(v, 2);
      v += __shfl_xor(v, 4);
      v += __shfl_xor(v, 8);
      if (n16 == 0) red[1][w][mt * 16 + quad * 4 + r] = v;
    }
  __syncthreads();

  float l_v[2][4];
#pragma unroll
  for (int mt = 0; mt < 2; ++mt)
#pragma unroll
    for (int r = 0; r < 4; ++r) {
      const int row = mt * 16 + quad * 4 + r;
      l_v[mt][r] = red[1][0][row] + red[1][1][row] + red[1][2][row] + red[1][3][row];
    }

  f4_t oacc[2][16];
#pragma unroll
  for (int mt = 0; mt < 2; ++mt)
#pragma unroll
    for (int nt = 0; nt < 16; ++nt) oacc[mt][nt] = fzero;

  for (int kc = 0; kc < 16; ++kc) {
    bf8_t pa0 = *(const bf8_t*)&fragP[n16][kc * 32 + quad * 8];
    bf8_t pa1 = *(const bf8_t*)&fragP[16 + n16][kc * 32 + quad * 8];
#pragma unroll
    for (int hc = 0; hc < 8; ++hc) {
      const __bf16* vt = Vc2B + ((size_t)kc * 1024 + w * 256 + hc * 32 + n16) * 32 + quad * 8;
      bf8_t vv0 = *(const bf8_t*)(vt);
      bf8_t vv1 = *(const bf8_t*)(vt + 16 * 32);
      oacc[0][hc * 2]     = __builtin_amdgcn_mfma_f32_16x16x32_bf16(
          pa0, vv0, oacc[0][hc * 2], 0, 0, 0);
      oacc[1][hc * 2]     = __builtin_amdgcn_mfma_f32_16x16x32_bf16(
          pa1, vv0, oacc[1][hc * 2], 0, 0, 0);
      oacc[0][hc * 2 + 1] = __builtin_amdgcn_mfma_f32_16x16x32_bf16(
          pa0, vv1, oacc[0][hc * 2 + 1], 0, 0, 0);
      oacc[1][hc * 2 + 1] = __builtin_amdgcn_mfma_f32_16x16x32_bf16(
          pa1, vv1, oacc[1][hc * 2 + 1], 0, 0, 0);
    }
  }

  float* ob = Out + ((size_t)b * Ln + l0) * Hn;
#pragma unroll
  for (int mt = 0; mt < 2; ++mt)
#pragma unroll
    for (int r = 0; r < 4; ++r) {
      const int row = mt * 16 + quad * 4 + r;
      const float inv = 1.f / l_v[mt][r];
#pragma unroll
      for (int nt = 0; nt < 16; ++nt) {
        ob[(size_t)row * Hn + w * 256 + nt * 16 + n16] = oacc[mt][nt][r] * inv;
      }
    }
}

// ---------------------------------------------------------------------------
// R1 kernel, kept verbatim as last-resort fallback (raw inputs).
// ---------------------------------------------------------------------------
__global__ __launch_bounds__(256, 2)
void mla_fused(const float* __restrict__ X, const int* __restrict__ AM,
               const float* __restrict__ W, float* __restrict__ Out) {
  const int bl   = blockIdx.x;
  const int b    = bl >> 4;
  const int l0   = (bl & 15) * 32;
  const int tid  = threadIdx.x;
  const int w    = tid >> 6;
  const int lane = tid & 63;
  const int n16  = lane & 15;
  const int quad = lane >> 4;

  __shared__ __bf16 fragP[32][136];
  __shared__ __bf16 fragV[4][32][136];
  __shared__ float  red[2][4][32];

  const f4_t fzero = {0.f, 0.f, 0.f, 0.f};
  const f4_t fneg  = {NEGINF, NEGINF, NEGINF, NEGINF};

  f4_t oacc[2][16];
#pragma unroll
  for (int mt = 0; mt < 2; ++mt)
#pragma unroll
    for (int nt = 0; nt < 16; ++nt) oacc[mt][nt] = fzero;

  float m_pr[2][4], l_pr[2][4];
#pragma unroll
  for (int mt = 0; mt < 2; ++mt)
#pragma unroll
    for (int r = 0; r < 4; ++r) { m_pr[mt][r] = -3e38f; l_pr[mt][r] = 0.f; }

  const float* Xb = X + (size_t)b * Sn * Hn;

  for (int step = 0; step < 4; ++step) {
    const int s0 = step * 128;

    f4_t sacc[2][2];
    sacc[0][0] = fzero; sacc[0][1] = fzero; sacc[1][0] = fzero; sacc[1][1] = fzero;

    const float* q0 = W  + (size_t)(l0 + n16) * Hn + quad * 8;
    const float* q1 = q0 + 16 * Hn;
    const float* k0 = Xb + (size_t)(s0 + w * 32 + n16) * Hn + quad * 8;
    const float* k1 = k0 + 16 * Hn;

    for (int hk = 0; hk < Hn; hk += 32) {
      bf8_t qh[2], ql[2], kh[2], kl[2];
      {
        f4_t a0 = *(const f4_t*)(q0 + hk);
        f4_t a1 = *(const f4_t*)(q0 + hk + 4);
        f4_t a2 = *(const f4_t*)(q1 + hk);
        f4_t a3 = *(const f4_t*)(q1 + hk + 4);
        f4_t c0 = *(const f4_t*)(k0 + hk);
        f4_t c1 = *(const f4_t*)(k0 + hk + 4);
        f4_t c2 = *(const f4_t*)(k1 + hk);
        f4_t c3 = *(const f4_t*)(k1 + hk + 4);
        split8(a0, a1, qh[0], ql[0]);
        split8(a2, a3, qh[1], ql[1]);
        split8(c0, c1, kh[0], kl[0]);
        split8(c2, c3, kh[1], kl[1]);
      }
#pragma unroll
      for (int mt = 0; mt < 2; ++mt)
#pragma unroll
        for (int nt = 0; nt < 2; ++nt) {
          f4_t c = sacc[mt][nt];
          c = __builtin_amdgcn_mfma_f32_16x16x32_bf16(qh[mt], kh[nt], c, 0, 0, 0);
          c = __builtin_amdgcn_mfma_f32_16x16x32_bf16(qh[mt], kl[nt], c, 0, 0, 0);
          c = __builtin_amdgcn_mfma_f32_16x16x32_bf16(ql[mt], kh[nt], c, 0, 0, 0);
          sacc[mt][nt] = c;
        }
    }

    {
      const int* mrow = AM + b * Sn + s0 + w * 32 + n16;
      int mk0 = mrow[0];
      int mk1 = mrow[16];
      if (!mk0) { sacc[0][0] = fneg; sacc[1][0] = fneg; }
      if (!mk1) { sacc[0][1] = fneg; sacc[1][1] = fneg; }
    }

    float rmx[2][4];
#pragma unroll
    for (int mt = 0; mt < 2; ++mt)
#pragma unroll
      for (int r = 0; r < 4; ++r) {
        float v = fmaxf(sacc[mt][0][r], sacc[mt][1][r]);
        v = fmaxf(v, __shfl_xor(v, 1));
        v = fmaxf(v, __shfl_xor(v, 2));
        v = fmaxf(v, __shfl_xor(v, 4));
        v = fmaxf(v, __shfl_xor(v, 8));
        rmx[mt][r] = v;
      }
    if (n16 == 0) {
#pragma unroll
      for (int mt = 0; mt < 2; ++mt)
#pragma unroll
        for (int r = 0; r < 4; ++r)
          red[0][w][mt * 16 + quad * 4 + r] = rmx[mt][r];
    }
    __syncthreads();

    float al[2][4], psum[2][4];
#pragma unroll
    for (int mt = 0; mt < 2; ++mt)
#pragma unroll
      for (int r = 0; r < 4; ++r) {
        const int row = mt * 16 + quad * 4 + r;
        float bm = fmaxf(fmaxf(red[0][0][row], red[0][1][row]),
                         fmaxf(red[0][2][row], red[0][3][row]));
        float mn = fmaxf(m_pr[mt][r], bm);
        al[mt][r] = __expf(m_pr[mt][r] - mn);
        m_pr[mt][r] = mn;
        psum[mt][r] = 0.f;
      }

#pragma unroll
    for (int mt = 0; mt < 2; ++mt)
#pragma unroll
      for (int nt = 0; nt < 2; ++nt)
#pragma unroll
        for (int r = 0; r < 4; ++r) {
          const int row = mt * 16 + quad * 4 + r;
          float p = __expf(sacc[mt][nt][r] - m_pr[mt][r]);
          psum[mt][r] += p;
          fragP[row][w * 32 + nt * 16 + n16] = (__bf16)p;
        }

#pragma unroll
    for (int mt = 0; mt < 2; ++mt)
#pragma unroll
      for (int r = 0; r < 4; ++r) {
        float v = psum[mt][r];
        v += __shfl_xor(v, 1);
        v += __shfl_xor(v, 2);
        v += __shfl_xor(v, 4);
        v += __shfl_xor(v, 8);
        if (n16 == 0) red[1][w][mt * 16 + quad * 4 + r] = v;
      }
    __syncthreads();

#pragma unroll
    for (int mt = 0; mt < 2; ++mt)
#pragma unroll
      for (int r = 0; r < 4; ++r) {
        const int row = mt * 16 + quad * 4 + r;
        float bs = red[1][0][row] + red[1][1][row] + red[1][2][row] + red[1][3][row];
        l_pr[mt][r] = l_pr[mt][r] * al[mt][r] + bs;
      }
#pragma unroll
    for (int mt = 0; mt < 2; ++mt)
#pragma unroll
      for (int nt = 0; nt < 16; ++nt)
#pragma unroll
        for (int r = 0; r < 4; ++r) oacc[mt][nt][r] *= al[mt][r];

    const int colg = lane & 7;
    const int sg   = lane >> 3;
    for (int hc = 0; hc < 8; ++hc) {
      const int h0 = w * 256 + hc * 32;
      const float* vsrc = Xb + (size_t)(s0 + sg * 4) * Hn + h0 + colg * 4;
#pragma unroll
      for (int it = 0; it < 4; ++it) {
        const float* p = vsrc + (size_t)(it * 32) * Hn;
        f4_t r0v = *(const f4_t*)(p);
        f4_t r1v = *(const f4_t*)(p + Hn);
        f4_t r2v = *(const f4_t*)(p + 2 * Hn);
        f4_t r3v = *(const f4_t*)(p + 3 * Hn);
        const int si = it * 32 + sg * 4;
#pragma unroll
        for (int cix = 0; cix < 4; ++cix) {
          bf4_t v;
          v[0] = (__bf16)r0v[cix];
          v[1] = (__bf16)r1v[cix];
          v[2] = (__bf16)r2v[cix];
          v[3] = (__bf16)r3v[cix];
          *(bf4_t*)&fragV[w][colg * 4 + cix][si] = v;
        }
      }
#pragma unroll
      for (int kk = 0; kk < 4; ++kk) {
        bf8_t pa0 = *(const bf8_t*)&fragP[n16][kk * 32 + quad * 8];
        bf8_t pa1 = *(const bf8_t*)&fragP[16 + n16][kk * 32 + quad * 8];
#pragma unroll
        for (int ntl = 0; ntl < 2; ++ntl) {
          bf8_t vv = *(const bf8_t*)&fragV[w][ntl * 16 + n16][kk * 32 + quad * 8];
          oacc[0][hc * 2 + ntl] =
              __builtin_amdgcn_mfma_f32_16x16x32_bf16(pa0, vv, oacc[0][hc * 2 + ntl], 0, 0, 0);
          oacc[1][hc * 2 + ntl] =
              __builtin_amdgcn_mfma_f32_16x16x32_bf16(pa1, vv, oacc[1][hc * 2 + ntl], 0, 0, 0);
        }
      }
    }
  }

  float* ob = Out + ((size_t)b * Ln + l0) * Hn;
#pragma unroll
  for (int mt = 0; mt < 2; ++mt)
#pragma unroll
    for (int r = 0; r < 4; ++r) {
      const int row = mt * 16 + quad * 4 + r;
      const float inv = 1.f / l_pr[mt][r];
#pragma unroll
      for (int nt = 0; nt < 16; ++nt) {
        ob[(size_t)row * Hn + w * 256 + nt * 16 + n16] = oacc[mt][nt][r] * inv;
      }
    }
}

extern "C" void kernel_launch(void* const* d_in, const int* in_sizes, int n_in,
                              void* d_out, int out_size, void* d_ws, size_t ws_size,
                              hipStream_t stream) {
  (void)in_sizes; (void)n_in; (void)out_size;
  const float* X  = (const float*)d_in[0];   // sequence_output [64,512,1024]
  const int*   AM = (const int*)d_in[1];     // attention_mask  [64,512]
  const float* W  = (const float*)d_in[2];   // attention_weights [512,1024]
  float* Out = (float*)d_out;                // [64,512,1024]

  // ws layout: XhiC 64MiB | XloC 64MiB | Vc2 64MiB | WhiC 1MiB | WloC 1MiB |
  //            Pws 32MiB | Lws 128KiB
  const size_t SZ_X = (size_t)Bn * Sn * Hn * sizeof(__bf16);  // 67108864
  const size_t SZ_W = (size_t)Ln * Hn * sizeof(__bf16);       // 1048576
  const size_t SZ_P = (size_t)Bn * Sn * Ln * sizeof(__bf16);  // 33554432
  const size_t SZ_L = (size_t)Bn * Ln * sizeof(float);        // 131072
  const size_t NEED_MID  = 3 * SZ_X + 2 * SZ_W;               // 203423744
  const size_t NEED_FULL = NEED_MID + SZ_P + SZ_L;            // 237109248

  if (d_ws != nullptr && ws_size >= NEED_MID) {
    char* wsb = (char*)d_ws;
    __bf16* XhiC = (__bf16*)(wsb);
    __bf16* XloC = (__bf16*)(wsb + SZ_X);
    __bf16* Vc2  = (__bf16*)(wsb + 2 * SZ_X);
    __bf16* WhiC = (__bf16*)(wsb + 3 * SZ_X);
    __bf16* WloC = (__bf16*)(wsb + 3 * SZ_X + SZ_W);
    prep_x<<<dim3(2048), dim3(256), 0, stream>>>(X, XhiC, XloC, Vc2);
    prep_w<<<dim3(256), dim3(256), 0, stream>>>(W, WhiC, WloC);
    if (ws_size >= NEED_FULL) {
      __bf16* Pws = (__bf16*)(wsb + 3 * SZ_X + 2 * SZ_W);
      float*  Lws = (float*)(wsb + 3 * SZ_X + 2 * SZ_W + SZ_P);
      mla_qk<<<dim3(512), dim3(512), 0, stream>>>(XhiC, XloC, AM, WhiC, WloC,
                                                  Pws, Lws);
      mla_pv<<<dim3(2048), dim3(256), 0, stream>>>(Pws, Vc2, Lws, Out);
    } else {
      mla_fused4<<<dim3(64 * 16), dim3(256), 0, stream>>>(XhiC, XloC, Vc2, AM,
                                                          WhiC, WloC, Out);
    }
  } else {
    mla_fused<<<dim3(64 * 16), dim3(256), 0, stream>>>(X, AM, W, Out);
  }
}